// Round 2
// baseline (10054.343 us; speedup 1.0000x reference)
//
#include <hip/hip_runtime.h>
#include <cstddef>

#define NN 10000
#define NE 160000
#define DD 128
#define NG 16

// ---------------------------------------------------------------- sh (edge spherical harmonics) + node-attr accumulation
__global__ void sh_kernel(const float* __restrict__ pos, const int* __restrict__ send,
                          const int* __restrict__ recv, float* __restrict__ ea,
                          float* __restrict__ naS, int E) {
  int e = blockIdx.x * 256 + threadIdx.x;
  if (e >= E) return;
  int s = send[e], r = recv[e];
  float rx = pos[s*3+0] - pos[r*3+0];
  float ry = pos[s*3+1] - pos[r*3+1];
  float rz = pos[s*3+2] - pos[r*3+2];
  float nrm = sqrtf(rx*rx + ry*ry + rz*rz) + 1e-8f;
  float x = rx / nrm, y = ry / nrm, z = rz / nrm;
  float x2 = x*x, y2 = y*y, z2 = z*z;
  float sh[16];
  sh[0] = 1.f;
  sh[1] = 1.7320508f * x;
  sh[2] = 1.7320508f * y;
  sh[3] = 1.7320508f * z;
  sh[4] = 3.8729833f * x * y;
  sh[5] = 3.8729833f * y * z;
  sh[6] = 1.118034f * (3.f * z2 - 1.f);
  sh[7] = 3.8729833f * x * z;
  sh[8] = 1.9364917f * (x2 - y2);
  sh[9] = 2.0916501f * y * (3.f * x2 - y2);
  sh[10] = 10.2469508f * x * y * z;
  sh[11] = 1.6201852f * y * (5.f * z2 - 1.f);
  sh[12] = 1.3228757f * (5.f * z2 - 3.f) * z;
  sh[13] = 1.6201852f * x * (5.f * z2 - 1.f);
  sh[14] = 5.1234754f * z * (x2 - y2);
  sh[15] = 2.0916501f * x * (x2 - 3.f * y2);
  float* ep = ea + (size_t)e * 16;
  *(float4*)(ep+0)  = make_float4(sh[0], sh[1], sh[2], sh[3]);
  *(float4*)(ep+4)  = make_float4(sh[4], sh[5], sh[6], sh[7]);
  *(float4*)(ep+8)  = make_float4(sh[8], sh[9], sh[10], sh[11]);
  *(float4*)(ep+12) = make_float4(sh[12], sh[13], sh[14], sh[15]);
  float* np = naS + (size_t)r * 16;
  #pragma unroll
  for (int k = 0; k < 16; ++k) atomicAdd(np + k, sh[k]);
}

__global__ void na_fin(float* __restrict__ na, const int* __restrict__ deg) {
  int idx = blockIdx.x * 256 + threadIdx.x;   // NN*16 total
  int n = idx >> 4, k = idx & 15;
  float c = fmaxf((float)deg[n], 1.f);
  float v = na[idx] / c;
  na[idx] = (k == 0) ? 1.f : v;
}

// ---------------------------------------------------------------- CSR build (reused across layers)
__global__ void count_k(const int* __restrict__ recv, int* __restrict__ deg, int E) {
  int e = blockIdx.x * 256 + threadIdx.x;
  if (e < E) atomicAdd(&deg[recv[e]], 1);
}

__global__ void scan_k(const int* __restrict__ deg, int* __restrict__ off, int* __restrict__ cur) {
  __shared__ int part[256];
  int tid = threadIdx.x;
  int base = tid * 40;
  int s = 0;
  for (int j = 0; j < 40; ++j) { int i = base + j; if (i < NN) s += deg[i]; }
  part[tid] = s;
  __syncthreads();
  if (tid == 0) {
    int run = 0;
    for (int i = 0; i < 256; ++i) { int v = part[i]; part[i] = run; run += v; }
  }
  __syncthreads();
  int run = part[tid];
  for (int j = 0; j < 40; ++j) {
    int i = base + j;
    if (i < NN) { off[i] = run; cur[i] = run; run += deg[i]; }
  }
  if (tid == 255) off[NN] = run;
}

__global__ void fill_k(const int* __restrict__ recv, int* __restrict__ cur,
                       int* __restrict__ csr, int E) {
  int e = blockIdx.x * 256 + threadIdx.x;
  if (e < E) { int p = atomicAdd(&cur[recv[e]], 1); csr[p] = e; }
}

// ---------------------------------------------------------------- node-level tensor-product GEMM (small M)
// ACT: 0 = A@Wx (+bias if non-null); 1 = (A@Wx+b)*(gate@Wa); 2 = silu of that
template<int KX, int ACT>
__launch_bounds__(256, 2)
__global__ void tp_gemm(const float* __restrict__ A, const float* __restrict__ gate,
                        const float* __restrict__ Wx, const float* __restrict__ Wa,
                        const float* __restrict__ bias, float* __restrict__ out, int M)
{
  constexpr int BK = 32;
  __shared__ float Asub[BK][64];
  __shared__ float Wsub[BK][128];
  __shared__ float Gt[ACT ? 64 : 1][ACT ? 16 : 1];
  __shared__ float WaS[ACT ? 16 : 1][ACT ? 128 : 1];

  const int tid = threadIdx.x;
  const int m0 = blockIdx.x * 64;
  const int col0 = (tid & 15) * 8;
  const int e0 = (tid >> 4) * 4;

  if constexpr (ACT > 0) {
    int e = tid >> 2, q = (tid & 3) * 4;
    int row = m0 + e; if (row >= M) row = M - 1;
    *(float4*)&Gt[e][q] = *(const float4*)(gate + (size_t)row * 16 + q);
    int wr = tid >> 4, wc = (tid & 15) * 8;
    *(float4*)&WaS[wr][wc]     = *(const float4*)(Wa + wr * 128 + wc);
    *(float4*)&WaS[wr][wc + 4] = *(const float4*)(Wa + wr * 128 + wc + 4);
  }

  float acc[4][8];
  #pragma unroll
  for (int i = 0; i < 4; ++i)
    #pragma unroll
    for (int j = 0; j < 8; ++j) acc[i][j] = 0.f;

  for (int k0 = 0; k0 < KX; k0 += BK) {
    __syncthreads();
    {
      int el = tid >> 2, koff = (tid & 3) * 8;
      int row = m0 + el; if (row >= M) row = M - 1;
      #pragma unroll
      for (int h4 = 0; h4 < 2; ++h4) {
        int k = k0 + koff + h4 * 4;
        if (k < KX) {
          float4 v = *(const float4*)(A + (size_t)row * KX + k);
          int kl = k - k0;
          Asub[kl+0][el] = v.x; Asub[kl+1][el] = v.y;
          Asub[kl+2][el] = v.z; Asub[kl+3][el] = v.w;
        }
      }
      int wr = tid >> 3, wc = (tid & 7) * 16;
      int k = k0 + wr;
      if (k < KX) {
        const float* wsrc = Wx + (size_t)k * 128 + wc;
        *(float4*)&Wsub[wr][wc]      = *(const float4*)(wsrc);
        *(float4*)&Wsub[wr][wc + 4]  = *(const float4*)(wsrc + 4);
        *(float4*)&Wsub[wr][wc + 8]  = *(const float4*)(wsrc + 8);
        *(float4*)&Wsub[wr][wc + 12] = *(const float4*)(wsrc + 12);
      }
    }
    __syncthreads();
    const int kc = (KX - k0 >= BK) ? BK : (KX - k0);
    for (int kk = 0; kk < kc; ++kk) {
      float4 a4 = *(const float4*)&Asub[kk][e0];
      float4 w0 = *(const float4*)&Wsub[kk][col0];
      float4 w1 = *(const float4*)&Wsub[kk][col0 + 4];
      float av[4] = {a4.x, a4.y, a4.z, a4.w};
      float wv[8] = {w0.x, w0.y, w0.z, w0.w, w1.x, w1.y, w1.z, w1.w};
      #pragma unroll
      for (int i = 0; i < 4; ++i)
        #pragma unroll
        for (int j = 0; j < 8; ++j) acc[i][j] = fmaf(av[i], wv[j], acc[i][j]);
    }
  }

  float gac[4][8];
  if constexpr (ACT > 0) {
    #pragma unroll
    for (int i = 0; i < 4; ++i)
      #pragma unroll
      for (int j = 0; j < 8; ++j) gac[i][j] = 0.f;
    #pragma unroll
    for (int k = 0; k < 16; ++k) {
      float4 w0 = *(const float4*)&WaS[k][col0];
      float4 w1 = *(const float4*)&WaS[k][col0 + 4];
      float wv[8] = {w0.x, w0.y, w0.z, w0.w, w1.x, w1.y, w1.z, w1.w};
      #pragma unroll
      for (int i = 0; i < 4; ++i) {
        float a = Gt[e0 + i][k];
        #pragma unroll
        for (int j = 0; j < 8; ++j) gac[i][j] = fmaf(a, wv[j], gac[i][j]);
      }
    }
  }

  float bv[8];
  if (bias) {
    float4 b0 = *(const float4*)(bias + col0);
    float4 b1 = *(const float4*)(bias + col0 + 4);
    bv[0]=b0.x; bv[1]=b0.y; bv[2]=b0.z; bv[3]=b0.w;
    bv[4]=b1.x; bv[5]=b1.y; bv[6]=b1.z; bv[7]=b1.w;
  } else {
    #pragma unroll
    for (int j = 0; j < 8; ++j) bv[j] = 0.f;
  }

  #pragma unroll
  for (int i = 0; i < 4; ++i) {
    int row = m0 + e0 + i;
    float res[8];
    #pragma unroll
    for (int j = 0; j < 8; ++j) {
      float t = acc[i][j] + bv[j];
      if constexpr (ACT > 0) t = t * gac[i][j];
      if constexpr (ACT == 2) t = t / (1.f + __expf(-t));
      res[j] = t;
    }
    if (row < M) {
      float* op = out + (size_t)row * 128 + col0;
      *(float4*)op       = make_float4(res[0], res[1], res[2], res[3]);
      *(float4*)(op + 4) = make_float4(res[4], res[5], res[6], res[7]);
    }
  }
}

// ---------------------------------------------------------------- fused m1-build + m2 GEMM + BN stats
// Per block: 128 edges × 128 cols. m1 tile lives only in LDS.
// A layout: As[row*128 + (col ^ sax(row))], sax(row) = ((row>>3)&3)<<3  (bank-conflict-free)
// thread: rg = tid>>4 (rows rg*8..+7), cg = tid&15, cols = cg*4 + {0..3, 64..67}
__device__ __forceinline__ void gate88(const float* __restrict__ Wa, const float* eaTl,
                                       int rg, int c0, float g[8][8]) {
  #pragma unroll
  for (int i = 0; i < 8; ++i)
    #pragma unroll
    for (int j = 0; j < 8; ++j) g[i][j] = 0.f;
  #pragma unroll
  for (int a = 0; a < 16; ++a) {
    float4 e0v = *(const float4*)&eaTl[a*132 + rg*8];
    float4 e1v = *(const float4*)&eaTl[a*132 + rg*8 + 4];
    float4 w0 = *(const float4*)(Wa + a*128 + c0);
    float4 w1 = *(const float4*)(Wa + a*128 + c0 + 64);
    float ev[8] = {e0v.x, e0v.y, e0v.z, e0v.w, e1v.x, e1v.y, e1v.z, e1v.w};
    float wv[8] = {w0.x, w0.y, w0.z, w0.w, w1.x, w1.y, w1.z, w1.w};
    #pragma unroll
    for (int i = 0; i < 8; ++i)
      #pragma unroll
      for (int j = 0; j < 8; ++j) g[i][j] = fmaf(ev[i], wv[j], g[i][j]);
  }
}

__launch_bounds__(256, 1)
__global__ void m12_fused(const float* __restrict__ Hr, const float* __restrict__ Hs,
                          const int* __restrict__ send, const int* __restrict__ recv,
                          const float* __restrict__ dist, const float* __restrict__ ea,
                          const float* __restrict__ w256, const float* __restrict__ W2,
                          const float* __restrict__ Wa1, const float* __restrict__ Wa2,
                          const float* __restrict__ b2, float* __restrict__ mout,
                          double* __restrict__ bn_sum, double* __restrict__ bn_sq)
{
  __shared__ float As[128*128];
  __shared__ float Ws[64*128];
  __shared__ float eaT[16*132];
  __shared__ float bS[512];
  __shared__ float bQ[512];
  __shared__ int   recvS[128];
  __shared__ int   sendS[128];
  __shared__ float distS[128];

  const int tid = threadIdx.x;
  const int e0b = blockIdx.x * 128;
  const int rg = tid >> 4;            // 0..15
  const int cg = tid & 15;            // 0..15
  const int c0 = cg * 4;
  const int sax = (rg & 3) << 3;

  if (tid < 128) {
    sendS[tid] = send[e0b + tid];
    recvS[tid] = recv[e0b + tid];
    distS[tid] = dist[e0b + tid];
  }
  {
    int et = tid >> 1, hf = (tid & 1) * 8;
    const float* ep = ea + (size_t)(e0b + et) * 16 + hf;
    float4 v0 = *(const float4*)(ep);
    float4 v1 = *(const float4*)(ep + 4);
    eaT[(hf+0)*132+et] = v0.x; eaT[(hf+1)*132+et] = v0.y;
    eaT[(hf+2)*132+et] = v0.z; eaT[(hf+3)*132+et] = v0.w;
    eaT[(hf+4)*132+et] = v1.x; eaT[(hf+5)*132+et] = v1.y;
    eaT[(hf+6)*132+et] = v1.z; eaT[(hf+7)*132+et] = v1.w;
  }
  __syncthreads();

  // ---- gate1 + m1 build into LDS ----
  {
    float g1[8][8];
    gate88(Wa1, eaT, rg, c0, g1);
    float4 wq0 = *(const float4*)(w256 + c0);
    float4 wq1 = *(const float4*)(w256 + c0 + 64);
    float wq[8] = {wq0.x, wq0.y, wq0.z, wq0.w, wq1.x, wq1.y, wq1.z, wq1.w};
    #pragma unroll
    for (int i = 0; i < 8; ++i) {
      int row = rg * 8 + i;
      int rid = recvS[row], sid = sendS[row];
      float dv = distS[row];
      const float* hr = Hr + (size_t)rid * 128;
      const float* hs = Hs + (size_t)sid * 128;
      float4 p0 = *(const float4*)(hr + c0);
      float4 p1 = *(const float4*)(hr + c0 + 64);
      float4 q0 = *(const float4*)(hs + c0);
      float4 q1 = *(const float4*)(hs + c0 + 64);
      float tv[8] = {p0.x+q0.x, p0.y+q0.y, p0.z+q0.z, p0.w+q0.w,
                     p1.x+q1.x, p1.y+q1.y, p1.z+q1.z, p1.w+q1.w};
      float rr[8];
      #pragma unroll
      for (int j = 0; j < 8; ++j) {
        float t = fmaf(dv, wq[j], tv[j]) * g1[i][j];
        rr[j] = t / (1.f + __expf(-t));          // silu
      }
      int ca = c0 ^ sax;
      *(float4*)&As[row*128 + ca]      = make_float4(rr[0], rr[1], rr[2], rr[3]);
      *(float4*)&As[row*128 + ca + 64] = make_float4(rr[4], rr[5], rr[6], rr[7]);
    }
  }

  // ---- m2 main GEMM: acc = A @ W2 ----
  float acc[8][8];
  #pragma unroll
  for (int i = 0; i < 8; ++i)
    #pragma unroll
    for (int j = 0; j < 8; ++j) acc[i][j] = 0.f;

  for (int h = 0; h < 2; ++h) {
    int k0 = h * 64;
    __syncthreads();
    {
      int cw = (tid & 31) * 4;
      int r0 = tid >> 5;
      #pragma unroll
      for (int it = 0; it < 8; ++it) {
        int r = it * 8 + r0;
        *(float4*)&Ws[r*128 + cw] = *(const float4*)(W2 + (size_t)(k0 + r) * 128 + cw);
      }
    }
    __syncthreads();
    #pragma unroll 2
    for (int s = 0; s < 16; ++s) {
      int kb = k0 + s * 4;
      float4 af[8];
      #pragma unroll
      for (int i = 0; i < 8; ++i)
        af[i] = *(const float4*)&As[(rg*8+i)*128 + (kb ^ sax)];
      float4 wf0[4], wf1[4];
      #pragma unroll
      for (int kk = 0; kk < 4; ++kk) {
        wf0[kk] = *(const float4*)&Ws[(s*4+kk)*128 + c0];
        wf1[kk] = *(const float4*)&Ws[(s*4+kk)*128 + c0 + 64];
      }
      #pragma unroll
      for (int kk = 0; kk < 4; ++kk) {
        float4 w0 = wf0[kk], w1 = wf1[kk];
        #pragma unroll
        for (int i = 0; i < 8; ++i) {
          float av = ((const float*)&af[i])[kk];
          acc[i][0] = fmaf(av, w0.x, acc[i][0]);
          acc[i][1] = fmaf(av, w0.y, acc[i][1]);
          acc[i][2] = fmaf(av, w0.z, acc[i][2]);
          acc[i][3] = fmaf(av, w0.w, acc[i][3]);
          acc[i][4] = fmaf(av, w1.x, acc[i][4]);
          acc[i][5] = fmaf(av, w1.y, acc[i][5]);
          acc[i][6] = fmaf(av, w1.z, acc[i][6]);
          acc[i][7] = fmaf(av, w1.w, acc[i][7]);
        }
      }
    }
  }

  // ---- epilogue: gate2, bias, silu, BN stats, store ----
  float g2[8][8];
  gate88(Wa2, eaT, rg, c0, g2);
  float4 b20 = *(const float4*)(b2 + c0);
  float4 b21 = *(const float4*)(b2 + c0 + 64);
  float bvv[8] = {b20.x, b20.y, b20.z, b20.w, b21.x, b21.y, b21.z, b21.w};
  float sloc[8], qloc[8];
  #pragma unroll
  for (int j = 0; j < 8; ++j) { sloc[j] = 0.f; qloc[j] = 0.f; }

  #pragma unroll
  for (int i = 0; i < 8; ++i) {
    int row = rg * 8 + i;
    float rr[8];
    #pragma unroll
    for (int j = 0; j < 8; ++j) {
      float t = (acc[i][j] + bvv[j]) * g2[i][j];
      t = t / (1.f + __expf(-t));
      rr[j] = t;
      sloc[j] += t;
      qloc[j] = fmaf(t, t, qloc[j]);
    }
    float* op = mout + (size_t)(e0b + row) * 128;
    *(float4*)(op + c0)      = make_float4(rr[0], rr[1], rr[2], rr[3]);
    *(float4*)(op + c0 + 64) = make_float4(rr[4], rr[5], rr[6], rr[7]);
  }

  const int lane = tid & 63, wv_ = tid >> 6;
  #pragma unroll
  for (int j = 0; j < 8; ++j) {
    float s = sloc[j], q = qloc[j];
    s += __shfl_xor(s, 16); q += __shfl_xor(q, 16);
    s += __shfl_xor(s, 32); q += __shfl_xor(q, 32);
    if (lane < 16) {
      int col = (lane * 4) + (j & 3) + (j >> 2) * 64;
      bS[wv_ * 128 + col] = s;
      bQ[wv_ * 128 + col] = q;
    }
  }
  __syncthreads();
  if (tid < 128) {
    float s = bS[tid] + bS[128 + tid] + bS[256 + tid] + bS[384 + tid];
    float q = bQ[tid] + bQ[128 + tid] + bQ[256 + tid] + bQ[384 + tid];
    atomicAdd(&bn_sum[tid], (double)s);
    atomicAdd(&bn_sq[tid], (double)q);
  }
}

// ---------------------------------------------------------------- BN finalize
__global__ void bn_fin(const double* __restrict__ s, const double* __restrict__ q,
                       const float* __restrict__ g, const float* __restrict__ b,
                       float* __restrict__ sc, float* __restrict__ sh) {
  int c = threadIdx.x;
  double mu = s[c] * (1.0 / NE);
  double var = q[c] * (1.0 / NE) - mu * mu;
  if (var < 0.0) var = 0.0;
  float scale = (float)((double)g[c] / sqrt(var + 1e-5));
  sc[c] = scale;
  sh[c] = b[c] - (float)mu * scale;
}

// ---------------------------------------------------------------- fused BN-apply + attention + CSR-gather agg + softmax + ucat
__global__ void att_csr(const float* __restrict__ m, const float* __restrict__ sc,
                        const float* __restrict__ sh, const float* __restrict__ ea,
                        const float* __restrict__ iWx, const float* __restrict__ iWa,
                        const float* __restrict__ ibp,
                        const int* __restrict__ off, const int* __restrict__ csr,
                        const float* __restrict__ h, float* __restrict__ ucat) {
  int wave = threadIdx.x >> 6, lane = threadIdx.x & 63;
  int n = blockIdx.x * 4 + wave;
  if (n >= NN) return;
  float2 scv = *(const float2*)(sc + lane * 2);
  float2 shv = *(const float2*)(sh + lane * 2);
  float2 wv  = *(const float2*)(iWx + lane * 2);
  float wa = (lane < 16) ? iWa[lane] : 0.f;
  float ib = ibp[0];
  int o0 = off[n], o1 = off[n + 1];
  float acc0 = 0.f, acc1 = 0.f;
  for (int i = o0; i < o1; ++i) {
    int e = csr[i];
    float2 mv = *(const float2*)(m + (size_t)e * 128 + lane * 2);
    float a0 = fmaf(mv.x, scv.x, shv.x);
    float a1 = fmaf(mv.y, scv.y, shv.y);
    float s1 = a0 * wv.x + a1 * wv.y;
    float s2 = (lane < 16) ? ea[(size_t)e * 16 + lane] * wa : 0.f;
    #pragma unroll
    for (int o = 32; o > 0; o >>= 1) { s1 += __shfl_xor(s1, o); s2 += __shfl_xor(s2, o); }
    float att = 1.f / (1.f + __expf(-(s1 + ib) * s2));
    acc0 = fmaf(a0, att, acc0);
    acc1 = fmaf(a1, att, acc1);
  }
  // softmax over the 128 dims + build ucat = [softmax(agg)*h | agg]
  float mx = fmaxf(acc0, acc1);
  #pragma unroll
  for (int o = 32; o > 0; o >>= 1) mx = fmaxf(mx, __shfl_xor(mx, o));
  float ex0 = __expf(acc0 - mx), ex1 = __expf(acc1 - mx);
  float s = ex0 + ex1;
  #pragma unroll
  for (int o = 32; o > 0; o >>= 1) s += __shfl_xor(s, o);
  float inv = 1.f / s;
  float2 hv = *(const float2*)(h + (size_t)n * 128 + lane * 2);
  *(float2*)(ucat + (size_t)n * 256 + lane * 2)       = make_float2(ex0 * inv * hv.x, ex1 * inv * hv.y);
  *(float2*)(ucat + (size_t)n * 256 + 128 + lane * 2) = make_float2(acc0, acc1);
}

// ---------------------------------------------------------------- graph pooling + head
__global__ void pool_k(const float* __restrict__ h, const int* __restrict__ batch,
                       float* __restrict__ gp, int N) {
  int g = blockIdx.x, j = threadIdx.x;
  int a = 0, b = N;
  while (a < b) { int mid = (a + b) >> 1; if (batch[mid] < g) a = mid + 1; else b = mid; }
  int lo = a;
  a = lo; b = N;
  while (a < b) { int mid = (a + b) >> 1; if (batch[mid] < g + 1) a = mid + 1; else b = mid; }
  int hi = a;
  float s = 0.f;
  for (int n = lo; n < hi; ++n) s += h[(size_t)n * 128 + j];
  gp[g * 128 + j] = s;
}

__global__ void pp1_k(const float* __restrict__ gp, const float* __restrict__ W,
                      const float* __restrict__ b, float* __restrict__ gact) {
  __shared__ float gs[NG * 128];
  for (int i = threadIdx.x; i < NG * 128; i += 256) gs[i] = gp[i];
  __syncthreads();
  for (int r = 0; r < 8; ++r) {
    int o = threadIdx.x + r * 256;
    int g = o >> 7, j = o & 127;
    float s = b[j];
    for (int k = 0; k < 128; ++k) s = fmaf(gs[g * 128 + k], W[k * 128 + j], s);
    gact[o] = s / (1.f + __expf(-s));
  }
}

__global__ void pp2_k(const float* __restrict__ gact, const float* __restrict__ w,
                      const float* __restrict__ b, float* __restrict__ out) {
  int t = threadIdx.x;
  if (t < NG) {
    float s = b[0];
    for (int j = 0; j < 128; ++j) s = fmaf(gact[t * 128 + j], w[j], s);
    out[t] = s;
  }
}

// ---------------------------------------------------------------- host
extern "C" void kernel_launch(void* const* d_in, const int* in_sizes, int n_in,
                              void* d_out, int out_size, void* d_ws, size_t ws_size,
                              hipStream_t stream)
{
  auto F = [&](int i) { return (const float*)d_in[i]; };
  auto I = [&](int i) { return (const int*)d_in[i]; };
  const float* x = F(0);
  const float* pos = F(1);
  const int* batch = I(2);
  const int* iei = I(3);
  const float* iea = F(4);
  const int* eei = I(5);
  const float* eea = F(6);
  const float* embinWx = F(7);  const float* embinWa = F(8);  const float* embinB = F(9);
  const float* emboutWx = F(10); const float* emboutWa = F(11); const float* emboutB = F(12);
  const float* m1Wx = F(13); const float* m1Wa = F(14); const float* m1B = F(15);
  const float* m2Wx = F(16); const float* m2Wa = F(17); const float* m2B = F(18);
  const float* bnG = F(19); const float* bnB = F(20);
  const float* infWx = F(21); const float* infWa = F(22); const float* infB = F(23);
  const float* uWx = F(24); const float* uWa = F(25); const float* uB = F(26);
  const float* ppWx = F(27); const float* ppWa = F(28); const float* ppB = F(29);
  const float* pp1W = F(30); const float* pp1B = F(31);
  const float* pp2W = F(32); const float* pp2B = F(33);
  float* out = (float*)d_out;

  float* ws = (float*)d_ws;
  size_t off = 0;
  auto alloc = [&](size_t n) { float* p = ws + off; off += (n + 63) & ~(size_t)63; return p; };
  float* eaI   = alloc((size_t)NE * 16);
  float* naI   = alloc((size_t)NN * 16);
  float* eaE   = alloc((size_t)NE * 16);
  float* naE   = alloc((size_t)NN * 16);
  float* hA    = alloc((size_t)NN * DD);
  float* hB    = alloc((size_t)NN * DD);
  float* nodeT = alloc((size_t)NN * 256);   // Hr|Hs during m12, then reused as ucat
  float* mbuf  = alloc((size_t)NE * DD);
  float* bnSC  = alloc(DD);
  float* bnSH  = alloc(DD);
  float* gp    = alloc(NG * DD);
  float* gact  = alloc(NG * DD);
  double* bnSum = (double*)alloc(512);      // 128+128 doubles
  double* bnSq  = bnSum + 128;
  int* degI = (int*)alloc(NN);
  int* degE = (int*)alloc(NN);
  int* offI = (int*)alloc(NN + 64);
  int* offE = (int*)alloc(NN + 64);
  int* curI = (int*)alloc(NN);
  int* curE = (int*)alloc(NN);
  int* csrI = (int*)alloc(NE);
  int* csrE = (int*)alloc(NE);

  float* Hr = nodeT;
  float* Hs = nodeT + (size_t)NN * DD;
  float* ucat = nodeT;

  hipMemsetAsync(naI, 0, (size_t)NN * 16 * 4, stream);
  hipMemsetAsync(naE, 0, (size_t)NN * 16 * 4, stream);
  hipMemsetAsync(degI, 0, NN * 4, stream);
  hipMemsetAsync(degE, 0, NN * 4, stream);
  hipMemsetAsync(gp, 0, NG * DD * 4, stream);

  const int* recvI = iei + NE;
  const int* recvE = eei + NE;

  count_k<<<(NE + 255) / 256, 256, 0, stream>>>(recvI, degI, NE);
  count_k<<<(NE + 255) / 256, 256, 0, stream>>>(recvE, degE, NE);
  scan_k<<<1, 256, 0, stream>>>(degI, offI, curI);
  scan_k<<<1, 256, 0, stream>>>(degE, offE, curE);
  fill_k<<<(NE + 255) / 256, 256, 0, stream>>>(recvI, curI, csrI, NE);
  fill_k<<<(NE + 255) / 256, 256, 0, stream>>>(recvE, curE, csrE, NE);

  sh_kernel<<<NE / 256, 256, 0, stream>>>(pos, iei, recvI, eaI, naI, NE);
  sh_kernel<<<NE / 256, 256, 0, stream>>>(pos, eei, recvE, eaE, naE, NE);
  na_fin<<<NN * 16 / 256, 256, 0, stream>>>(naI, degI);
  na_fin<<<NN * 16 / 256, 256, 0, stream>>>(naE, degE);

  const int gN = (NN + 63) / 64;

  tp_gemm<16, 2><<<gN, 256, 0, stream>>>(x, naI, embinWx, embinWa, embinB, hA, NN);

  float* hin = hA;
  float* hout = hB;
  for (int l = 0; l < 6; ++l) {
    const bool internal = (l < 3);
    const int* send = internal ? iei : eei;
    const int* recv = internal ? recvI : recvE;
    const float* dist = internal ? iea : eea;
    const float* ea = internal ? eaI : eaE;
    const float* na = internal ? naI : naE;
    const int* coff = internal ? offI : offE;
    const int* ccsr = internal ? csrI : csrE;

    if (l == 3) {
      tp_gemm<128, 1><<<gN, 256, 0, stream>>>(hin, naE, emboutWx, emboutWa, emboutB, hout, NN);
      float* t = hin; hin = hout; hout = t;
    }

    hipMemsetAsync(bnSum, 0, 2048, stream);

    const float* Wx1 = m1Wx + (size_t)l * 257 * 128;
    tp_gemm<128, 0><<<gN, 256, 0, stream>>>(hin, nullptr, Wx1, nullptr,
                                            m1B + l * 128, Hr, NN);
    tp_gemm<128, 0><<<gN, 256, 0, stream>>>(hin, nullptr, Wx1 + 128 * 128, nullptr,
                                            nullptr, Hs, NN);
    m12_fused<<<NE / 128, 256, 0, stream>>>(
        Hr, Hs, send, recv, dist, ea,
        Wx1 + 256 * 128,
        m2Wx + (size_t)l * 128 * 128,
        m1Wa + (size_t)l * 16 * 128,
        m2Wa + (size_t)l * 16 * 128,
        m2B + l * 128,
        mbuf, bnSum, bnSq);
    bn_fin<<<1, 128, 0, stream>>>(bnSum, bnSq, bnG + l * 128, bnB + l * 128, bnSC, bnSH);
    att_csr<<<(NN + 3) / 4, 256, 0, stream>>>(mbuf, bnSC, bnSH, ea,
                                              infWx + l * 128, infWa + l * 16, infB + l,
                                              coff, ccsr, hin, ucat);
    tp_gemm<256, 2><<<gN, 256, 0, stream>>>(ucat, na,
                                            uWx + (size_t)l * 256 * 128,
                                            uWa + (size_t)l * 16 * 128,
                                            uB + l * 128, hout, NN);
    float* t = hin; hin = hout; hout = t;
  }

  tp_gemm<128, 2><<<gN, 256, 0, stream>>>(hin, naE, ppWx, ppWa, ppB, hout, NN);
  pool_k<<<NG, 128, 0, stream>>>(hout, batch, gp, NN);
  pp1_k<<<1, 256, 0, stream>>>(gp, pp1W, pp1B, gact);
  pp2_k<<<1, 64, 0, stream>>>(gact, pp2W, pp2B, out);
}

// Round 5
// 2210.412 us; speedup vs baseline: 4.5486x; 4.5486x over previous
//
#include <hip/hip_runtime.h>
#include <cstddef>

#define NN 10000
#define NE 160000
#define DD 128
#define NG 16

// ---------------------------------------------------------------- sh (edge spherical harmonics) + node-attr accumulation
__global__ void sh_kernel(const float* __restrict__ pos, const int* __restrict__ send,
                          const int* __restrict__ recv, float* __restrict__ ea,
                          float* __restrict__ naS, int E) {
  int e = blockIdx.x * 256 + threadIdx.x;
  if (e >= E) return;
  int s = send[e], r = recv[e];
  float rx = pos[s*3+0] - pos[r*3+0];
  float ry = pos[s*3+1] - pos[r*3+1];
  float rz = pos[s*3+2] - pos[r*3+2];
  float nrm = sqrtf(rx*rx + ry*ry + rz*rz) + 1e-8f;
  float x = rx / nrm, y = ry / nrm, z = rz / nrm;
  float x2 = x*x, y2 = y*y, z2 = z*z;
  float sh[16];
  sh[0] = 1.f;
  sh[1] = 1.7320508f * x;
  sh[2] = 1.7320508f * y;
  sh[3] = 1.7320508f * z;
  sh[4] = 3.8729833f * x * y;
  sh[5] = 3.8729833f * y * z;
  sh[6] = 1.118034f * (3.f * z2 - 1.f);
  sh[7] = 3.8729833f * x * z;
  sh[8] = 1.9364917f * (x2 - y2);
  sh[9] = 2.0916501f * y * (3.f * x2 - y2);
  sh[10] = 10.2469508f * x * y * z;
  sh[11] = 1.6201852f * y * (5.f * z2 - 1.f);
  sh[12] = 1.3228757f * (5.f * z2 - 3.f) * z;
  sh[13] = 1.6201852f * x * (5.f * z2 - 1.f);
  sh[14] = 5.1234754f * z * (x2 - y2);
  sh[15] = 2.0916501f * x * (x2 - 3.f * y2);
  float* ep = ea + (size_t)e * 16;
  *(float4*)(ep+0)  = make_float4(sh[0], sh[1], sh[2], sh[3]);
  *(float4*)(ep+4)  = make_float4(sh[4], sh[5], sh[6], sh[7]);
  *(float4*)(ep+8)  = make_float4(sh[8], sh[9], sh[10], sh[11]);
  *(float4*)(ep+12) = make_float4(sh[12], sh[13], sh[14], sh[15]);
  float* np = naS + (size_t)r * 16;
  #pragma unroll
  for (int k = 0; k < 16; ++k) atomicAdd(np + k, sh[k]);
}

__global__ void na_fin(float* __restrict__ na, const int* __restrict__ deg) {
  int idx = blockIdx.x * 256 + threadIdx.x;   // NN*16 total
  int n = idx >> 4, k = idx & 15;
  float c = fmaxf((float)deg[n], 1.f);
  float v = na[idx] / c;
  na[idx] = (k == 0) ? 1.f : v;
}

// ---------------------------------------------------------------- CSR build (reused across layers)
__global__ void count_k(const int* __restrict__ recv, int* __restrict__ deg, int E) {
  int e = blockIdx.x * 256 + threadIdx.x;
  if (e < E) atomicAdd(&deg[recv[e]], 1);
}

__global__ void scan_k(const int* __restrict__ deg, int* __restrict__ off, int* __restrict__ cur) {
  __shared__ int part[256];
  int tid = threadIdx.x;
  int base = tid * 40;
  int s = 0;
  for (int j = 0; j < 40; ++j) { int i = base + j; if (i < NN) s += deg[i]; }
  part[tid] = s;
  __syncthreads();
  if (tid == 0) {
    int run = 0;
    for (int i = 0; i < 256; ++i) { int v = part[i]; part[i] = run; run += v; }
  }
  __syncthreads();
  int run = part[tid];
  for (int j = 0; j < 40; ++j) {
    int i = base + j;
    if (i < NN) { off[i] = run; cur[i] = run; run += deg[i]; }
  }
  if (tid == 255) off[NN] = run;
}

__global__ void fill_k(const int* __restrict__ recv, int* __restrict__ cur,
                       int* __restrict__ csr, int E) {
  int e = blockIdx.x * 256 + threadIdx.x;
  if (e < E) { int p = atomicAdd(&cur[recv[e]], 1); csr[p] = e; }
}

// ---------------------------------------------------------------- node-level tensor-product GEMM body (round-1 proven, unrolled path restored)
// ACT: 0 = A@Wx (+bias); 1 = (A@Wx+b)*(gate@Wa); 2 = silu of that
template<int KX, int ACT>
__device__ __forceinline__ void tpg_body(const float* __restrict__ A, const float* __restrict__ gate,
                                         const float* __restrict__ Wx, const float* __restrict__ Wa,
                                         const float* __restrict__ bias, float* __restrict__ out, int M)
{
  constexpr int BK = 32;
  __shared__ float Asub[BK][64];
  __shared__ float Wsub[BK][128];
  __shared__ float Gt[ACT ? 64 : 1][ACT ? 16 : 1];
  __shared__ float WaS[ACT ? 16 : 1][ACT ? 128 : 1];

  const int tid = threadIdx.x;
  const int m0 = blockIdx.x * 64;
  const int col0 = (tid & 15) * 8;
  const int e0 = (tid >> 4) * 4;

  if constexpr (ACT > 0) {
    int e = tid >> 2, q = (tid & 3) * 4;
    int row = m0 + e; if (row >= M) row = M - 1;
    *(float4*)&Gt[e][q] = *(const float4*)(gate + (size_t)row * 16 + q);
    int wr = tid >> 4, wc = (tid & 15) * 8;
    *(float4*)&WaS[wr][wc]     = *(const float4*)(Wa + wr * 128 + wc);
    *(float4*)&WaS[wr][wc + 4] = *(const float4*)(Wa + wr * 128 + wc + 4);
  }

  float acc[4][8];
  #pragma unroll
  for (int i = 0; i < 4; ++i)
    #pragma unroll
    for (int j = 0; j < 8; ++j) acc[i][j] = 0.f;

  for (int k0 = 0; k0 < KX; k0 += BK) {
    __syncthreads();
    {
      int el = tid >> 2, koff = (tid & 3) * 8;
      int row = m0 + el; if (row >= M) row = M - 1;
      #pragma unroll
      for (int h4 = 0; h4 < 2; ++h4) {
        int k = k0 + koff + h4 * 4;
        if (k < KX) {
          float4 v = *(const float4*)(A + (size_t)row * KX + k);
          int kl = k - k0;
          Asub[kl+0][el] = v.x; Asub[kl+1][el] = v.y;
          Asub[kl+2][el] = v.z; Asub[kl+3][el] = v.w;
        }
      }
      int wr = tid >> 3, wc = (tid & 7) * 16;
      int k = k0 + wr;
      if (k < KX) {
        const float* wsrc = Wx + (size_t)k * 128 + wc;
        *(float4*)&Wsub[wr][wc]      = *(const float4*)(wsrc);
        *(float4*)&Wsub[wr][wc + 4]  = *(const float4*)(wsrc + 4);
        *(float4*)&Wsub[wr][wc + 8]  = *(const float4*)(wsrc + 8);
        *(float4*)&Wsub[wr][wc + 12] = *(const float4*)(wsrc + 12);
      }
    }
    __syncthreads();
    const int kc = (KX - k0 >= BK) ? BK : (KX - k0);
    if (kc == BK) {
      #pragma unroll
      for (int kk = 0; kk < BK; ++kk) {
        float4 a4 = *(const float4*)&Asub[kk][e0];
        float4 w0 = *(const float4*)&Wsub[kk][col0];
        float4 w1 = *(const float4*)&Wsub[kk][col0 + 4];
        float av[4] = {a4.x, a4.y, a4.z, a4.w};
        float wv[8] = {w0.x, w0.y, w0.z, w0.w, w1.x, w1.y, w1.z, w1.w};
        #pragma unroll
        for (int i = 0; i < 4; ++i)
          #pragma unroll
          for (int j = 0; j < 8; ++j) acc[i][j] = fmaf(av[i], wv[j], acc[i][j]);
      }
    } else {
      for (int kk = 0; kk < kc; ++kk) {
        float4 a4 = *(const float4*)&Asub[kk][e0];
        float4 w0 = *(const float4*)&Wsub[kk][col0];
        float4 w1 = *(const float4*)&Wsub[kk][col0 + 4];
        float av[4] = {a4.x, a4.y, a4.z, a4.w};
        float wv[8] = {w0.x, w0.y, w0.z, w0.w, w1.x, w1.y, w1.z, w1.w};
        #pragma unroll
        for (int i = 0; i < 4; ++i)
          #pragma unroll
          for (int j = 0; j < 8; ++j) acc[i][j] = fmaf(av[i], wv[j], acc[i][j]);
      }
    }
  }

  float gac[4][8];
  if constexpr (ACT > 0) {
    #pragma unroll
    for (int i = 0; i < 4; ++i)
      #pragma unroll
      for (int j = 0; j < 8; ++j) gac[i][j] = 0.f;
    #pragma unroll
    for (int k = 0; k < 16; ++k) {
      float4 w0 = *(const float4*)&WaS[k][col0];
      float4 w1 = *(const float4*)&WaS[k][col0 + 4];
      float wv[8] = {w0.x, w0.y, w0.z, w0.w, w1.x, w1.y, w1.z, w1.w};
      #pragma unroll
      for (int i = 0; i < 4; ++i) {
        float a = Gt[e0 + i][k];
        #pragma unroll
        for (int j = 0; j < 8; ++j) gac[i][j] = fmaf(a, wv[j], gac[i][j]);
      }
    }
  }

  float bv[8];
  if (bias) {
    float4 b0 = *(const float4*)(bias + col0);
    float4 b1 = *(const float4*)(bias + col0 + 4);
    bv[0]=b0.x; bv[1]=b0.y; bv[2]=b0.z; bv[3]=b0.w;
    bv[4]=b1.x; bv[5]=b1.y; bv[6]=b1.z; bv[7]=b1.w;
  } else {
    #pragma unroll
    for (int j = 0; j < 8; ++j) bv[j] = 0.f;
  }

  #pragma unroll
  for (int i = 0; i < 4; ++i) {
    int row = m0 + e0 + i;
    float res[8];
    #pragma unroll
    for (int j = 0; j < 8; ++j) {
      float t = acc[i][j] + bv[j];
      if constexpr (ACT > 0) t = t * gac[i][j];
      if constexpr (ACT == 2) t = t / (1.f + __expf(-t));
      res[j] = t;
    }
    if (row < M) {
      float* op = out + (size_t)row * 128 + col0;
      *(float4*)op       = make_float4(res[0], res[1], res[2], res[3]);
      *(float4*)(op + 4) = make_float4(res[4], res[5], res[6], res[7]);
    }
  }
}

// Distinctly-named wrappers (profiling attribution)
__global__ __launch_bounds__(256, 2) void k_emb(const float* A, const float* gate,
    const float* Wx, const float* Wa, const float* bias, float* out, int M)
{ tpg_body<16, 2>(A, gate, Wx, Wa, bias, out, M); }

__global__ __launch_bounds__(256, 2) void k_embout(const float* A, const float* gate,
    const float* Wx, const float* Wa, const float* bias, float* out, int M)
{ tpg_body<128, 1>(A, gate, Wx, Wa, bias, out, M); }

__global__ __launch_bounds__(256, 2) void k_upd(const float* A, const float* gate,
    const float* Wx, const float* Wa, const float* bias, float* out, int M)
{ tpg_body<256, 2>(A, gate, Wx, Wa, bias, out, M); }

__global__ __launch_bounds__(256, 2) void k_pp(const float* A, const float* gate,
    const float* Wx, const float* Wa, const float* bias, float* out, int M)
{ tpg_body<128, 2>(A, gate, Wx, Wa, bias, out, M); }

// ---------------------------------------------------------------- dual-output node GEMM: out1 = A@W1 + b1, out2 = A@W2 (KX=128)
__global__ __launch_bounds__(256, 2)
void k_dual(const float* __restrict__ A, const float* __restrict__ W1,
            const float* __restrict__ W2, const float* __restrict__ b1,
            float* __restrict__ out1, float* __restrict__ out2, int M)
{
  constexpr int BK = 32;
  constexpr int KX = 128;
  __shared__ float Asub[BK][64];
  __shared__ float Wsub[BK][128];
  __shared__ float W2sub[BK][128];

  const int tid = threadIdx.x;
  const int m0 = blockIdx.x * 64;
  const int col0 = (tid & 15) * 8;
  const int e0 = (tid >> 4) * 4;

  float acc[4][8], acc2[4][8];
  #pragma unroll
  for (int i = 0; i < 4; ++i)
    #pragma unroll
    for (int j = 0; j < 8; ++j) { acc[i][j] = 0.f; acc2[i][j] = 0.f; }

  for (int k0 = 0; k0 < KX; k0 += BK) {
    __syncthreads();
    {
      int el = tid >> 2, koff = (tid & 3) * 8;
      int row = m0 + el; if (row >= M) row = M - 1;
      #pragma unroll
      for (int h4 = 0; h4 < 2; ++h4) {
        int k = k0 + koff + h4 * 4;
        float4 v = *(const float4*)(A + (size_t)row * KX + k);
        int kl = k - k0;
        Asub[kl+0][el] = v.x; Asub[kl+1][el] = v.y;
        Asub[kl+2][el] = v.z; Asub[kl+3][el] = v.w;
      }
      int wr = tid >> 3, wc = (tid & 7) * 16;
      int k = k0 + wr;
      const float* w1src = W1 + (size_t)k * 128 + wc;
      *(float4*)&Wsub[wr][wc]      = *(const float4*)(w1src);
      *(float4*)&Wsub[wr][wc + 4]  = *(const float4*)(w1src + 4);
      *(float4*)&Wsub[wr][wc + 8]  = *(const float4*)(w1src + 8);
      *(float4*)&Wsub[wr][wc + 12] = *(const float4*)(w1src + 12);
      const float* w2src = W2 + (size_t)k * 128 + wc;
      *(float4*)&W2sub[wr][wc]      = *(const float4*)(w2src);
      *(float4*)&W2sub[wr][wc + 4]  = *(const float4*)(w2src + 4);
      *(float4*)&W2sub[wr][wc + 8]  = *(const float4*)(w2src + 8);
      *(float4*)&W2sub[wr][wc + 12] = *(const float4*)(w2src + 12);
    }
    __syncthreads();
    #pragma unroll
    for (int kk = 0; kk < BK; ++kk) {
      float4 a4 = *(const float4*)&Asub[kk][e0];
      float4 w0 = *(const float4*)&Wsub[kk][col0];
      float4 w1 = *(const float4*)&Wsub[kk][col0 + 4];
      float4 u0 = *(const float4*)&W2sub[kk][col0];
      float4 u1 = *(const float4*)&W2sub[kk][col0 + 4];
      float av[4] = {a4.x, a4.y, a4.z, a4.w};
      float wv[8] = {w0.x, w0.y, w0.z, w0.w, w1.x, w1.y, w1.z, w1.w};
      float uv[8] = {u0.x, u0.y, u0.z, u0.w, u1.x, u1.y, u1.z, u1.w};
      #pragma unroll
      for (int i = 0; i < 4; ++i) {
        #pragma unroll
        for (int j = 0; j < 8; ++j) {
          acc[i][j]  = fmaf(av[i], wv[j], acc[i][j]);
          acc2[i][j] = fmaf(av[i], uv[j], acc2[i][j]);
        }
      }
    }
  }

  float4 b0 = *(const float4*)(b1 + col0);
  float4 b1v = *(const float4*)(b1 + col0 + 4);
  float bv[8] = {b0.x, b0.y, b0.z, b0.w, b1v.x, b1v.y, b1v.z, b1v.w};

  #pragma unroll
  for (int i = 0; i < 4; ++i) {
    int row = m0 + e0 + i;
    if (row < M) {
      float* o1 = out1 + (size_t)row * 128 + col0;
      float* o2 = out2 + (size_t)row * 128 + col0;
      *(float4*)o1       = make_float4(acc[i][0]+bv[0], acc[i][1]+bv[1], acc[i][2]+bv[2], acc[i][3]+bv[3]);
      *(float4*)(o1 + 4) = make_float4(acc[i][4]+bv[4], acc[i][5]+bv[5], acc[i][6]+bv[6], acc[i][7]+bv[7]);
      *(float4*)o2       = make_float4(acc2[i][0], acc2[i][1], acc2[i][2], acc2[i][3]);
      *(float4*)(o2 + 4) = make_float4(acc2[i][4], acc2[i][5], acc2[i][6], acc2[i][7]);
    }
  }
}

// ---------------------------------------------------------------- fused m1-build + m2 GEMM + BN stats
__device__ __forceinline__ void gate88(const float* __restrict__ Wa, const float* eaTl,
                                       int rg, int c0, float g[8][8]) {
  #pragma unroll
  for (int i = 0; i < 8; ++i)
    #pragma unroll
    for (int j = 0; j < 8; ++j) g[i][j] = 0.f;
  #pragma unroll
  for (int a = 0; a < 16; ++a) {
    float4 e0v = *(const float4*)&eaTl[a*132 + rg*8];
    float4 e1v = *(const float4*)&eaTl[a*132 + rg*8 + 4];
    float4 w0 = *(const float4*)(Wa + a*128 + c0);
    float4 w1 = *(const float4*)(Wa + a*128 + c0 + 64);
    float ev[8] = {e0v.x, e0v.y, e0v.z, e0v.w, e1v.x, e1v.y, e1v.z, e1v.w};
    float wv[8] = {w0.x, w0.y, w0.z, w0.w, w1.x, w1.y, w1.z, w1.w};
    #pragma unroll
    for (int i = 0; i < 8; ++i)
      #pragma unroll
      for (int j = 0; j < 8; ++j) g[i][j] = fmaf(ev[i], wv[j], g[i][j]);
  }
}

__launch_bounds__(256, 1)
__global__ void m12_fused(const float* __restrict__ Hr, const float* __restrict__ Hs,
                          const int* __restrict__ send, const int* __restrict__ recv,
                          const float* __restrict__ dist, const float* __restrict__ ea,
                          const float* __restrict__ w256, const float* __restrict__ W2,
                          const float* __restrict__ Wa1, const float* __restrict__ Wa2,
                          const float* __restrict__ b2, float* __restrict__ mout,
                          double* __restrict__ bn_sum, double* __restrict__ bn_sq)
{
  __shared__ float As[128*128];
  __shared__ float Ws[64*128];
  __shared__ float eaT[16*132];
  __shared__ float bS[512];
  __shared__ float bQ[512];
  __shared__ int   recvS[128];
  __shared__ int   sendS[128];
  __shared__ float distS[128];

  const int tid = threadIdx.x;
  const int e0b = blockIdx.x * 128;
  const int rg = tid >> 4;            // 0..15
  const int cg = tid & 15;            // 0..15
  const int c0 = cg * 4;
  const int sax = (rg & 3) << 3;

  if (tid < 128) {
    sendS[tid] = send[e0b + tid];
    recvS[tid] = recv[e0b + tid];
    distS[tid] = dist[e0b + tid];
  }
  {
    int et = tid >> 1, hf = (tid & 1) * 8;
    const float* ep = ea + (size_t)(e0b + et) * 16 + hf;
    float4 v0 = *(const float4*)(ep);
    float4 v1 = *(const float4*)(ep + 4);
    eaT[(hf+0)*132+et] = v0.x; eaT[(hf+1)*132+et] = v0.y;
    eaT[(hf+2)*132+et] = v0.z; eaT[(hf+3)*132+et] = v0.w;
    eaT[(hf+4)*132+et] = v1.x; eaT[(hf+5)*132+et] = v1.y;
    eaT[(hf+6)*132+et] = v1.z; eaT[(hf+7)*132+et] = v1.w;
  }
  __syncthreads();

  // ---- gate1 + m1 build into LDS ----
  {
    float g1[8][8];
    gate88(Wa1, eaT, rg, c0, g1);
    float4 wq0 = *(const float4*)(w256 + c0);
    float4 wq1 = *(const float4*)(w256 + c0 + 64);
    float wq[8] = {wq0.x, wq0.y, wq0.z, wq0.w, wq1.x, wq1.y, wq1.z, wq1.w};
    #pragma unroll
    for (int i = 0; i < 8; ++i) {
      int row = rg * 8 + i;
      int rid = recvS[row], sid = sendS[row];
      float dv = distS[row];
      const float* hr = Hr + (size_t)rid * 128;
      const float* hs = Hs + (size_t)sid * 128;
      float4 p0 = *(const float4*)(hr + c0);
      float4 p1 = *(const float4*)(hr + c0 + 64);
      float4 q0 = *(const float4*)(hs + c0);
      float4 q1 = *(const float4*)(hs + c0 + 64);
      float tv[8] = {p0.x+q0.x, p0.y+q0.y, p0.z+q0.z, p0.w+q0.w,
                     p1.x+q1.x, p1.y+q1.y, p1.z+q1.z, p1.w+q1.w};
      float rr[8];
      #pragma unroll
      for (int j = 0; j < 8; ++j) {
        float t = fmaf(dv, wq[j], tv[j]) * g1[i][j];
        rr[j] = t / (1.f + __expf(-t));          // silu
      }
      int ca = c0 ^ sax;
      *(float4*)&As[row*128 + ca]      = make_float4(rr[0], rr[1], rr[2], rr[3]);
      *(float4*)&As[row*128 + ca + 64] = make_float4(rr[4], rr[5], rr[6], rr[7]);
    }
  }

  // ---- m2 main GEMM: acc = A @ W2 ----
  float acc[8][8];
  #pragma unroll
  for (int i = 0; i < 8; ++i)
    #pragma unroll
    for (int j = 0; j < 8; ++j) acc[i][j] = 0.f;

  for (int h = 0; h < 2; ++h) {
    int k0 = h * 64;
    __syncthreads();
    {
      int cw = (tid & 31) * 4;
      int r0 = tid >> 5;
      #pragma unroll
      for (int it = 0; it < 8; ++it) {
        int r = it * 8 + r0;
        *(float4*)&Ws[r*128 + cw] = *(const float4*)(W2 + (size_t)(k0 + r) * 128 + cw);
      }
    }
    __syncthreads();
    #pragma unroll 2
    for (int s = 0; s < 16; ++s) {
      int kb = k0 + s * 4;
      float4 af[8];
      #pragma unroll
      for (int i = 0; i < 8; ++i)
        af[i] = *(const float4*)&As[(rg*8+i)*128 + ((kb & 127) ^ sax)];
      float4 wf0[4], wf1[4];
      #pragma unroll
      for (int kk = 0; kk < 4; ++kk) {
        wf0[kk] = *(const float4*)&Ws[(s*4+kk)*128 + c0];
        wf1[kk] = *(const float4*)&Ws[(s*4+kk)*128 + c0 + 64];
      }
      #pragma unroll
      for (int kk = 0; kk < 4; ++kk) {
        float4 w0 = wf0[kk], w1 = wf1[kk];
        #pragma unroll
        for (int i = 0; i < 8; ++i) {
          float av = ((const float*)&af[i])[kk];
          acc[i][0] = fmaf(av, w0.x, acc[i][0]);
          acc[i][1] = fmaf(av, w0.y, acc[i][1]);
          acc[i][2] = fmaf(av, w0.z, acc[i][2]);
          acc[i][3] = fmaf(av, w0.w, acc[i][3]);
          acc[i][4] = fmaf(av, w1.x, acc[i][4]);
          acc[i][5] = fmaf(av, w1.y, acc[i][5]);
          acc[i][6] = fmaf(av, w1.z, acc[i][6]);
          acc[i][7] = fmaf(av, w1.w, acc[i][7]);
        }
      }
    }
  }

  // ---- epilogue: gate2, bias, silu, BN stats, store ----
  float g2[8][8];
  gate88(Wa2, eaT, rg, c0, g2);
  float4 b20 = *(const float4*)(b2 + c0);
  float4 b21 = *(const float4*)(b2 + c0 + 64);
  float bvv[8] = {b20.x, b20.y, b20.z, b20.w, b21.x, b21.y, b21.z, b21.w};
  float sloc[8], qloc[8];
  #pragma unroll
  for (int j = 0; j < 8; ++j) { sloc[j] = 0.f; qloc[j] = 0.f; }

  #pragma unroll
  for (int i = 0; i < 8; ++i) {
    int row = rg * 8 + i;
    float rr[8];
    #pragma unroll
    for (int j = 0; j < 8; ++j) {
      float t = (acc[i][j] + bvv[j]) * g2[i][j];
      t = t / (1.f + __expf(-t));
      rr[j] = t;
      sloc[j] += t;
      qloc[j] = fmaf(t, t, qloc[j]);
    }
    float* op = mout + (size_t)(e0b + row) * 128;
    *(float4*)(op + c0)      = make_float4(rr[0], rr[1], rr[2], rr[3]);
    *(float4*)(op + c0 + 64) = make_float4(rr[4], rr[5], rr[6], rr[7]);
  }

  const int lane = tid & 63, wv_ = tid >> 6;
  #pragma unroll
  for (int j = 0; j < 8; ++j) {
    float s = sloc[j], q = qloc[j];
    s += __shfl_xor(s, 16); q += __shfl_xor(q, 16);
    s += __shfl_xor(s, 32); q += __shfl_xor(q, 32);
    if (lane < 16) {
      int col = (lane * 4) + (j & 3) + (j >> 2) * 64;
      bS[wv_ * 128 + col] = s;
      bQ[wv_ * 128 + col] = q;
    }
  }
  __syncthreads();
  if (tid < 128) {
    float s = bS[tid] + bS[128 + tid] + bS[256 + tid] + bS[384 + tid];
    float q = bQ[tid] + bQ[128 + tid] + bQ[256 + tid] + bQ[384 + tid];
    atomicAdd(&bn_sum[tid], (double)s);
    atomicAdd(&bn_sq[tid], (double)q);
  }
}

// ---------------------------------------------------------------- BN finalize
__global__ void bn_fin(const double* __restrict__ s, const double* __restrict__ q,
                       const float* __restrict__ g, const float* __restrict__ b,
                       float* __restrict__ sc, float* __restrict__ sh) {
  int c = threadIdx.x;
  double mu = s[c] * (1.0 / NE);
  double var = q[c] * (1.0 / NE) - mu * mu;
  if (var < 0.0) var = 0.0;
  float scale = (float)((double)g[c] / sqrt(var + 1e-5));
  sc[c] = scale;
  sh[c] = b[c] - (float)mu * scale;
}

// ---------------------------------------------------------------- fused BN-apply + attention + CSR-gather agg + softmax + ucat
__global__ void att_csr(const float* __restrict__ m, const float* __restrict__ sc,
                        const float* __restrict__ sh, const float* __restrict__ ea,
                        const float* __restrict__ iWx, const float* __restrict__ iWa,
                        const float* __restrict__ ibp,
                        const int* __restrict__ off, const int* __restrict__ csr,
                        const float* __restrict__ h, float* __restrict__ ucat) {
  int wave = threadIdx.x >> 6, lane = threadIdx.x & 63;
  int n = blockIdx.x * 4 + wave;
  if (n >= NN) return;
  float2 scv = *(const float2*)(sc + lane * 2);
  float2 shv = *(const float2*)(sh + lane * 2);
  float2 wv  = *(const float2*)(iWx + lane * 2);
  float wa = (lane < 16) ? iWa[lane] : 0.f;
  float ib = ibp[0];
  int o0 = off[n], o1 = off[n + 1];
  float acc0 = 0.f, acc1 = 0.f;
  for (int i = o0; i < o1; ++i) {
    int e = csr[i];
    float2 mv = *(const float2*)(m + (size_t)e * 128 + lane * 2);
    float a0 = fmaf(mv.x, scv.x, shv.x);
    float a1 = fmaf(mv.y, scv.y, shv.y);
    float s1 = a0 * wv.x + a1 * wv.y;
    float s2 = (lane < 16) ? ea[(size_t)e * 16 + lane] * wa : 0.f;
    #pragma unroll
    for (int o = 32; o > 0; o >>= 1) { s1 += __shfl_xor(s1, o); s2 += __shfl_xor(s2, o); }
    float att = 1.f / (1.f + __expf(-(s1 + ib) * s2));
    acc0 = fmaf(a0, att, acc0);
    acc1 = fmaf(a1, att, acc1);
  }
  float mx = fmaxf(acc0, acc1);
  #pragma unroll
  for (int o = 32; o > 0; o >>= 1) mx = fmaxf(mx, __shfl_xor(mx, o));
  float ex0 = __expf(acc0 - mx), ex1 = __expf(acc1 - mx);
  float s = ex0 + ex1;
  #pragma unroll
  for (int o = 32; o > 0; o >>= 1) s += __shfl_xor(s, o);
  float inv = 1.f / s;
  float2 hv = *(const float2*)(h + (size_t)n * 128 + lane * 2);
  *(float2*)(ucat + (size_t)n * 256 + lane * 2)       = make_float2(ex0 * inv * hv.x, ex1 * inv * hv.y);
  *(float2*)(ucat + (size_t)n * 256 + 128 + lane * 2) = make_float2(acc0, acc1);
}

// ---------------------------------------------------------------- graph pooling + head
__global__ void pool_k(const float* __restrict__ h, const int* __restrict__ batch,
                       float* __restrict__ gp, int N) {
  int g = blockIdx.x, j = threadIdx.x;
  int a = 0, b = N;
  while (a < b) { int mid = (a + b) >> 1; if (batch[mid] < g) a = mid + 1; else b = mid; }
  int lo = a;
  a = lo; b = N;
  while (a < b) { int mid = (a + b) >> 1; if (batch[mid] < g + 1) a = mid + 1; else b = mid; }
  int hi = a;
  float s = 0.f;
  for (int n = lo; n < hi; ++n) s += h[(size_t)n * 128 + j];
  gp[g * 128 + j] = s;
}

__global__ void pp1_k(const float* __restrict__ gp, const float* __restrict__ W,
                      const float* __restrict__ b, float* __restrict__ gact) {
  __shared__ float gs[NG * 128];
  for (int i = threadIdx.x; i < NG * 128; i += 256) gs[i] = gp[i];
  __syncthreads();
  for (int r = 0; r < 8; ++r) {
    int o = threadIdx.x + r * 256;
    int g = o >> 7, j = o & 127;
    float s = b[j];
    for (int k = 0; k < 128; ++k) s = fmaf(gs[g * 128 + k], W[k * 128 + j], s);
    gact[o] = s / (1.f + __expf(-s));
  }
}

__global__ void pp2_k(const float* __restrict__ gact, const float* __restrict__ w,
                      const float* __restrict__ b, float* __restrict__ out) {
  int t = threadIdx.x;
  if (t < NG) {
    float s = b[0];
    for (int j = 0; j < 128; ++j) s = fmaf(gact[t * 128 + j], w[j], s);
    out[t] = s;
  }
}

// ---------------------------------------------------------------- host
extern "C" void kernel_launch(void* const* d_in, const int* in_sizes, int n_in,
                              void* d_out, int out_size, void* d_ws, size_t ws_size,
                              hipStream_t stream)
{
  auto F = [&](int i) { return (const float*)d_in[i]; };
  auto I = [&](int i) { return (const int*)d_in[i]; };
  const float* x = F(0);
  const float* pos = F(1);
  const int* batch = I(2);
  const int* iei = I(3);
  const float* iea = F(4);
  const int* eei = I(5);
  const float* eea = F(6);
  const float* embinWx = F(7);  const float* embinWa = F(8);  const float* embinB = F(9);
  const float* emboutWx = F(10); const float* emboutWa = F(11); const float* emboutB = F(12);
  const float* m1Wx = F(13); const float* m1Wa = F(14); const float* m1B = F(15);
  const float* m2Wx = F(16); const float* m2Wa = F(17); const float* m2B = F(18);
  const float* bnG = F(19); const float* bnB = F(20);
  const float* infWx = F(21); const float* infWa = F(22); const float* infB = F(23);
  const float* uWx = F(24); const float* uWa = F(25); const float* uB = F(26);
  const float* ppWx = F(27); const float* ppWa = F(28); const float* ppB = F(29);
  const float* pp1W = F(30); const float* pp1B = F(31);
  const float* pp2W = F(32); const float* pp2B = F(33);
  float* out = (float*)d_out;

  float* ws = (float*)d_ws;
  size_t off = 0;
  auto alloc = [&](size_t n) { float* p = ws + off; off += (n + 63) & ~(size_t)63; return p; };
  float* eaI   = alloc((size_t)NE * 16);
  float* naI   = alloc((size_t)NN * 16);
  float* eaE   = alloc((size_t)NE * 16);
  float* naE   = alloc((size_t)NN * 16);
  float* hA    = alloc((size_t)NN * DD);
  float* hB    = alloc((size_t)NN * DD);
  float* nodeT = alloc((size_t)NN * 256);   // Hr|Hs during m12, then reused as ucat
  float* mbuf  = alloc((size_t)NE * DD);
  float* bnSC  = alloc(DD);
  float* bnSH  = alloc(DD);
  float* gp    = alloc(NG * DD);
  float* gact  = alloc(NG * DD);
  double* bnSum = (double*)alloc(512);      // 128+128 doubles
  double* bnSq  = bnSum + 128;
  int* degI = (int*)alloc(NN);
  int* degE = (int*)alloc(NN);
  int* offI = (int*)alloc(NN + 64);
  int* offE = (int*)alloc(NN + 64);
  int* curI = (int*)alloc(NN);
  int* curE = (int*)alloc(NN);
  int* csrI = (int*)alloc(NE);
  int* csrE = (int*)alloc(NE);

  float* Hr = nodeT;
  float* Hs = nodeT + (size_t)NN * DD;
  float* ucat = nodeT;

  hipMemsetAsync(naI, 0, (size_t)NN * 16 * 4, stream);
  hipMemsetAsync(naE, 0, (size_t)NN * 16 * 4, stream);
  hipMemsetAsync(degI, 0, NN * 4, stream);
  hipMemsetAsync(degE, 0, NN * 4, stream);
  hipMemsetAsync(gp, 0, NG * DD * 4, stream);

  const int* recvI = iei + NE;
  const int* recvE = eei + NE;

  count_k<<<(NE + 255) / 256, 256, 0, stream>>>(recvI, degI, NE);
  count_k<<<(NE + 255) / 256, 256, 0, stream>>>(recvE, degE, NE);
  scan_k<<<1, 256, 0, stream>>>(degI, offI, curI);
  scan_k<<<1, 256, 0, stream>>>(degE, offE, curE);
  fill_k<<<(NE + 255) / 256, 256, 0, stream>>>(recvI, curI, csrI, NE);
  fill_k<<<(NE + 255) / 256, 256, 0, stream>>>(recvE, curE, csrE, NE);

  sh_kernel<<<NE / 256, 256, 0, stream>>>(pos, iei, recvI, eaI, naI, NE);
  sh_kernel<<<NE / 256, 256, 0, stream>>>(pos, eei, recvE, eaE, naE, NE);
  na_fin<<<NN * 16 / 256, 256, 0, stream>>>(naI, degI);
  na_fin<<<NN * 16 / 256, 256, 0, stream>>>(naE, degE);

  const int gN = (NN + 63) / 64;

  k_emb<<<gN, 256, 0, stream>>>(x, naI, embinWx, embinWa, embinB, hA, NN);

  float* hin = hA;
  float* hout = hB;
  for (int l = 0; l < 6; ++l) {
    const bool internal = (l < 3);
    const int* send = internal ? iei : eei;
    const int* recv = internal ? recvI : recvE;
    const float* dist = internal ? iea : eea;
    const float* ea = internal ? eaI : eaE;
    const float* na = internal ? naI : naE;
    const int* coff = internal ? offI : offE;
    const int* ccsr = internal ? csrI : csrE;

    if (l == 3) {
      k_embout<<<gN, 256, 0, stream>>>(hin, naE, emboutWx, emboutWa, emboutB, hout, NN);
      float* t = hin; hin = hout; hout = t;
    }

    hipMemsetAsync(bnSum, 0, 2048, stream);

    const float* Wx1 = m1Wx + (size_t)l * 257 * 128;
    k_dual<<<gN, 256, 0, stream>>>(hin, Wx1, Wx1 + 128 * 128, m1B + l * 128, Hr, Hs, NN);
    m12_fused<<<NE / 128, 256, 0, stream>>>(
        Hr, Hs, send, recv, dist, ea,
        Wx1 + 256 * 128,
        m2Wx + (size_t)l * 128 * 128,
        m1Wa + (size_t)l * 16 * 128,
        m2Wa + (size_t)l * 16 * 128,
        m2B + l * 128,
        mbuf, bnSum, bnSq);
    bn_fin<<<1, 128, 0, stream>>>(bnSum, bnSq, bnG + l * 128, bnB + l * 128, bnSC, bnSH);
    att_csr<<<(NN + 3) / 4, 256, 0, stream>>>(mbuf, bnSC, bnSH, ea,
                                              infWx + l * 128, infWa + l * 16, infB + l,
                                              coff, ccsr, hin, ucat);
    k_upd<<<gN, 256, 0, stream>>>(ucat, na,
                                  uWx + (size_t)l * 256 * 128,
                                  uWa + (size_t)l * 16 * 128,
                                  uB + l * 128, hout, NN);
    float* t = hin; hin = hout; hout = t;
  }

  k_pp<<<gN, 256, 0, stream>>>(hin, naE, ppWx, ppWa, ppB, hout, NN);
  pool_k<<<NG, 128, 0, stream>>>(hout, batch, gp, NN);
  pp1_k<<<1, 256, 0, stream>>>(gp, pp1W, pp1B, gact);
  pp2_k<<<1, 64, 0, stream>>>(gact, pp2W, pp2B, out);
}

// Round 6
// 2049.427 us; speedup vs baseline: 4.9059x; 1.0786x over previous
//
#include <hip/hip_runtime.h>
#include <cstddef>

#define NN 10000
#define NE 160000
#define DD 128
#define NG 16

// ---------------------------------------------------------------- sh (edge spherical harmonics) + node-attr accumulation
__global__ void sh_kernel(const float* __restrict__ pos, const int* __restrict__ send,
                          const int* __restrict__ recv, float* __restrict__ ea,
                          float* __restrict__ naS, int E) {
  int e = blockIdx.x * 256 + threadIdx.x;
  if (e >= E) return;
  int s = send[e], r = recv[e];
  float rx = pos[s*3+0] - pos[r*3+0];
  float ry = pos[s*3+1] - pos[r*3+1];
  float rz = pos[s*3+2] - pos[r*3+2];
  float nrm = sqrtf(rx*rx + ry*ry + rz*rz) + 1e-8f;
  float x = rx / nrm, y = ry / nrm, z = rz / nrm;
  float x2 = x*x, y2 = y*y, z2 = z*z;
  float sh[16];
  sh[0] = 1.f;
  sh[1] = 1.7320508f * x;
  sh[2] = 1.7320508f * y;
  sh[3] = 1.7320508f * z;
  sh[4] = 3.8729833f * x * y;
  sh[5] = 3.8729833f * y * z;
  sh[6] = 1.118034f * (3.f * z2 - 1.f);
  sh[7] = 3.8729833f * x * z;
  sh[8] = 1.9364917f * (x2 - y2);
  sh[9] = 2.0916501f * y * (3.f * x2 - y2);
  sh[10] = 10.2469508f * x * y * z;
  sh[11] = 1.6201852f * y * (5.f * z2 - 1.f);
  sh[12] = 1.3228757f * (5.f * z2 - 3.f) * z;
  sh[13] = 1.6201852f * x * (5.f * z2 - 1.f);
  sh[14] = 5.1234754f * z * (x2 - y2);
  sh[15] = 2.0916501f * x * (x2 - 3.f * y2);
  float* ep = ea + (size_t)e * 16;
  *(float4*)(ep+0)  = make_float4(sh[0], sh[1], sh[2], sh[3]);
  *(float4*)(ep+4)  = make_float4(sh[4], sh[5], sh[6], sh[7]);
  *(float4*)(ep+8)  = make_float4(sh[8], sh[9], sh[10], sh[11]);
  *(float4*)(ep+12) = make_float4(sh[12], sh[13], sh[14], sh[15]);
  float* np = naS + (size_t)r * 16;
  #pragma unroll
  for (int k = 0; k < 16; ++k) atomicAdd(np + k, sh[k]);
}

__global__ void na_fin(float* __restrict__ na, const int* __restrict__ deg) {
  int idx = blockIdx.x * 256 + threadIdx.x;   // NN*16 total
  int n = idx >> 4, k = idx & 15;
  float c = fmaxf((float)deg[n], 1.f);
  float v = na[idx] / c;
  na[idx] = (k == 0) ? 1.f : v;
}

// ---------------------------------------------------------------- CSR build (reused across layers)
__global__ void count_k(const int* __restrict__ recv, int* __restrict__ deg, int E) {
  int e = blockIdx.x * 256 + threadIdx.x;
  if (e < E) atomicAdd(&deg[recv[e]], 1);
}

__global__ void scan_k(const int* __restrict__ deg, int* __restrict__ off, int* __restrict__ cur) {
  __shared__ int part[256];
  int tid = threadIdx.x;
  int base = tid * 40;
  int s = 0;
  for (int j = 0; j < 40; ++j) { int i = base + j; if (i < NN) s += deg[i]; }
  part[tid] = s;
  __syncthreads();
  if (tid == 0) {
    int run = 0;
    for (int i = 0; i < 256; ++i) { int v = part[i]; part[i] = run; run += v; }
  }
  __syncthreads();
  int run = part[tid];
  for (int j = 0; j < 40; ++j) {
    int i = base + j;
    if (i < NN) { off[i] = run; cur[i] = run; run += deg[i]; }
  }
  if (tid == 255) off[NN] = run;
}

__global__ void fill_k(const int* __restrict__ recv, int* __restrict__ cur,
                       int* __restrict__ csr, int E) {
  int e = blockIdx.x * 256 + threadIdx.x;
  if (e < E) { int p = atomicAdd(&cur[recv[e]], 1); csr[p] = e; }
}

// ---------------------------------------------------------------- node-level tensor-product GEMM body (round-1 proven, unrolled path restored)
// ACT: 0 = A@Wx (+bias); 1 = (A@Wx+b)*(gate@Wa); 2 = silu of that
template<int KX, int ACT>
__device__ __forceinline__ void tpg_body(const float* __restrict__ A, const float* __restrict__ gate,
                                         const float* __restrict__ Wx, const float* __restrict__ Wa,
                                         const float* __restrict__ bias, float* __restrict__ out, int M)
{
  constexpr int BK = 32;
  __shared__ float Asub[BK][64];
  __shared__ float Wsub[BK][128];
  __shared__ float Gt[ACT ? 64 : 1][ACT ? 16 : 1];
  __shared__ float WaS[ACT ? 16 : 1][ACT ? 128 : 1];

  const int tid = threadIdx.x;
  const int m0 = blockIdx.x * 64;
  const int col0 = (tid & 15) * 8;
  const int e0 = (tid >> 4) * 4;

  if constexpr (ACT > 0) {
    int e = tid >> 2, q = (tid & 3) * 4;
    int row = m0 + e; if (row >= M) row = M - 1;
    *(float4*)&Gt[e][q] = *(const float4*)(gate + (size_t)row * 16 + q);
    int wr = tid >> 4, wc = (tid & 15) * 8;
    *(float4*)&WaS[wr][wc]     = *(const float4*)(Wa + wr * 128 + wc);
    *(float4*)&WaS[wr][wc + 4] = *(const float4*)(Wa + wr * 128 + wc + 4);
  }

  float acc[4][8];
  #pragma unroll
  for (int i = 0; i < 4; ++i)
    #pragma unroll
    for (int j = 0; j < 8; ++j) acc[i][j] = 0.f;

  for (int k0 = 0; k0 < KX; k0 += BK) {
    __syncthreads();
    {
      int el = tid >> 2, koff = (tid & 3) * 8;
      int row = m0 + el; if (row >= M) row = M - 1;
      #pragma unroll
      for (int h4 = 0; h4 < 2; ++h4) {
        int k = k0 + koff + h4 * 4;
        if (k < KX) {
          float4 v = *(const float4*)(A + (size_t)row * KX + k);
          int kl = k - k0;
          Asub[kl+0][el] = v.x; Asub[kl+1][el] = v.y;
          Asub[kl+2][el] = v.z; Asub[kl+3][el] = v.w;
        }
      }
      int wr = tid >> 3, wc = (tid & 7) * 16;
      int k = k0 + wr;
      if (k < KX) {
        const float* wsrc = Wx + (size_t)k * 128 + wc;
        *(float4*)&Wsub[wr][wc]      = *(const float4*)(wsrc);
        *(float4*)&Wsub[wr][wc + 4]  = *(const float4*)(wsrc + 4);
        *(float4*)&Wsub[wr][wc + 8]  = *(const float4*)(wsrc + 8);
        *(float4*)&Wsub[wr][wc + 12] = *(const float4*)(wsrc + 12);
      }
    }
    __syncthreads();
    const int kc = (KX - k0 >= BK) ? BK : (KX - k0);
    if (kc == BK) {
      #pragma unroll
      for (int kk = 0; kk < BK; ++kk) {
        float4 a4 = *(const float4*)&Asub[kk][e0];
        float4 w0 = *(const float4*)&Wsub[kk][col0];
        float4 w1 = *(const float4*)&Wsub[kk][col0 + 4];
        float av[4] = {a4.x, a4.y, a4.z, a4.w};
        float wv[8] = {w0.x, w0.y, w0.z, w0.w, w1.x, w1.y, w1.z, w1.w};
        #pragma unroll
        for (int i = 0; i < 4; ++i)
          #pragma unroll
          for (int j = 0; j < 8; ++j) acc[i][j] = fmaf(av[i], wv[j], acc[i][j]);
      }
    } else {
      for (int kk = 0; kk < kc; ++kk) {
        float4 a4 = *(const float4*)&Asub[kk][e0];
        float4 w0 = *(const float4*)&Wsub[kk][col0];
        float4 w1 = *(const float4*)&Wsub[kk][col0 + 4];
        float av[4] = {a4.x, a4.y, a4.z, a4.w};
        float wv[8] = {w0.x, w0.y, w0.z, w0.w, w1.x, w1.y, w1.z, w1.w};
        #pragma unroll
        for (int i = 0; i < 4; ++i)
          #pragma unroll
          for (int j = 0; j < 8; ++j) acc[i][j] = fmaf(av[i], wv[j], acc[i][j]);
      }
    }
  }

  float gac[4][8];
  if constexpr (ACT > 0) {
    #pragma unroll
    for (int i = 0; i < 4; ++i)
      #pragma unroll
      for (int j = 0; j < 8; ++j) gac[i][j] = 0.f;
    #pragma unroll
    for (int k = 0; k < 16; ++k) {
      float4 w0 = *(const float4*)&WaS[k][col0];
      float4 w1 = *(const float4*)&WaS[k][col0 + 4];
      float wv[8] = {w0.x, w0.y, w0.z, w0.w, w1.x, w1.y, w1.z, w1.w};
      #pragma unroll
      for (int i = 0; i < 4; ++i) {
        float a = Gt[e0 + i][k];
        #pragma unroll
        for (int j = 0; j < 8; ++j) gac[i][j] = fmaf(a, wv[j], gac[i][j]);
      }
    }
  }

  float bv[8];
  if (bias) {
    float4 b0 = *(const float4*)(bias + col0);
    float4 b1 = *(const float4*)(bias + col0 + 4);
    bv[0]=b0.x; bv[1]=b0.y; bv[2]=b0.z; bv[3]=b0.w;
    bv[4]=b1.x; bv[5]=b1.y; bv[6]=b1.z; bv[7]=b1.w;
  } else {
    #pragma unroll
    for (int j = 0; j < 8; ++j) bv[j] = 0.f;
  }

  #pragma unroll
  for (int i = 0; i < 4; ++i) {
    int row = m0 + e0 + i;
    float res[8];
    #pragma unroll
    for (int j = 0; j < 8; ++j) {
      float t = acc[i][j] + bv[j];
      if constexpr (ACT > 0) t = t * gac[i][j];
      if constexpr (ACT == 2) t = t / (1.f + __expf(-t));
      res[j] = t;
    }
    if (row < M) {
      float* op = out + (size_t)row * 128 + col0;
      *(float4*)op       = make_float4(res[0], res[1], res[2], res[3]);
      *(float4*)(op + 4) = make_float4(res[4], res[5], res[6], res[7]);
    }
  }
}

// Distinctly-named wrappers (profiling attribution)
__global__ __launch_bounds__(256, 2) void k_emb(const float* A, const float* gate,
    const float* Wx, const float* Wa, const float* bias, float* out, int M)
{ tpg_body<16, 2>(A, gate, Wx, Wa, bias, out, M); }

__global__ __launch_bounds__(256, 2) void k_embout(const float* A, const float* gate,
    const float* Wx, const float* Wa, const float* bias, float* out, int M)
{ tpg_body<128, 1>(A, gate, Wx, Wa, bias, out, M); }

__global__ __launch_bounds__(256, 2) void k_upd(const float* A, const float* gate,
    const float* Wx, const float* Wa, const float* bias, float* out, int M)
{ tpg_body<256, 2>(A, gate, Wx, Wa, bias, out, M); }

__global__ __launch_bounds__(256, 2) void k_pp(const float* A, const float* gate,
    const float* Wx, const float* Wa, const float* bias, float* out, int M)
{ tpg_body<128, 2>(A, gate, Wx, Wa, bias, out, M); }

// ---------------------------------------------------------------- dual-output node GEMM: out1 = A@W1 + b1, out2 = A@W2 (KX=128)
__global__ __launch_bounds__(256, 2)
void k_dual(const float* __restrict__ A, const float* __restrict__ W1,
            const float* __restrict__ W2, const float* __restrict__ b1,
            float* __restrict__ out1, float* __restrict__ out2, int M)
{
  constexpr int BK = 32;
  constexpr int KX = 128;
  __shared__ float Asub[BK][64];
  __shared__ float Wsub[BK][128];
  __shared__ float W2sub[BK][128];

  const int tid = threadIdx.x;
  const int m0 = blockIdx.x * 64;
  const int col0 = (tid & 15) * 8;
  const int e0 = (tid >> 4) * 4;

  float acc[4][8], acc2[4][8];
  #pragma unroll
  for (int i = 0; i < 4; ++i)
    #pragma unroll
    for (int j = 0; j < 8; ++j) { acc[i][j] = 0.f; acc2[i][j] = 0.f; }

  for (int k0 = 0; k0 < KX; k0 += BK) {
    __syncthreads();
    {
      int el = tid >> 2, koff = (tid & 3) * 8;
      int row = m0 + el; if (row >= M) row = M - 1;
      #pragma unroll
      for (int h4 = 0; h4 < 2; ++h4) {
        int k = k0 + koff + h4 * 4;
        float4 v = *(const float4*)(A + (size_t)row * KX + k);
        int kl = k - k0;
        Asub[kl+0][el] = v.x; Asub[kl+1][el] = v.y;
        Asub[kl+2][el] = v.z; Asub[kl+3][el] = v.w;
      }
      int wr = tid >> 3, wc = (tid & 7) * 16;
      int k = k0 + wr;
      const float* w1src = W1 + (size_t)k * 128 + wc;
      *(float4*)&Wsub[wr][wc]      = *(const float4*)(w1src);
      *(float4*)&Wsub[wr][wc + 4]  = *(const float4*)(w1src + 4);
      *(float4*)&Wsub[wr][wc + 8]  = *(const float4*)(w1src + 8);
      *(float4*)&Wsub[wr][wc + 12] = *(const float4*)(w1src + 12);
      const float* w2src = W2 + (size_t)k * 128 + wc;
      *(float4*)&W2sub[wr][wc]      = *(const float4*)(w2src);
      *(float4*)&W2sub[wr][wc + 4]  = *(const float4*)(w2src + 4);
      *(float4*)&W2sub[wr][wc + 8]  = *(const float4*)(w2src + 8);
      *(float4*)&W2sub[wr][wc + 12] = *(const float4*)(w2src + 12);
    }
    __syncthreads();
    #pragma unroll
    for (int kk = 0; kk < BK; ++kk) {
      float4 a4 = *(const float4*)&Asub[kk][e0];
      float4 w0 = *(const float4*)&Wsub[kk][col0];
      float4 w1 = *(const float4*)&Wsub[kk][col0 + 4];
      float4 u0 = *(const float4*)&W2sub[kk][col0];
      float4 u1 = *(const float4*)&W2sub[kk][col0 + 4];
      float av[4] = {a4.x, a4.y, a4.z, a4.w};
      float wv[8] = {w0.x, w0.y, w0.z, w0.w, w1.x, w1.y, w1.z, w1.w};
      float uv[8] = {u0.x, u0.y, u0.z, u0.w, u1.x, u1.y, u1.z, u1.w};
      #pragma unroll
      for (int i = 0; i < 4; ++i) {
        #pragma unroll
        for (int j = 0; j < 8; ++j) {
          acc[i][j]  = fmaf(av[i], wv[j], acc[i][j]);
          acc2[i][j] = fmaf(av[i], uv[j], acc2[i][j]);
        }
      }
    }
  }

  float4 b0 = *(const float4*)(b1 + col0);
  float4 b1v = *(const float4*)(b1 + col0 + 4);
  float bv[8] = {b0.x, b0.y, b0.z, b0.w, b1v.x, b1v.y, b1v.z, b1v.w};

  #pragma unroll
  for (int i = 0; i < 4; ++i) {
    int row = m0 + e0 + i;
    if (row < M) {
      float* o1 = out1 + (size_t)row * 128 + col0;
      float* o2 = out2 + (size_t)row * 128 + col0;
      *(float4*)o1       = make_float4(acc[i][0]+bv[0], acc[i][1]+bv[1], acc[i][2]+bv[2], acc[i][3]+bv[3]);
      *(float4*)(o1 + 4) = make_float4(acc[i][4]+bv[4], acc[i][5]+bv[5], acc[i][6]+bv[6], acc[i][7]+bv[7]);
      *(float4*)o2       = make_float4(acc2[i][0], acc2[i][1], acc2[i][2], acc2[i][3]);
      *(float4*)(o2 + 4) = make_float4(acc2[i][4], acc2[i][5], acc2[i][6], acc2[i][7]);
    }
  }
}

// ---------------------------------------------------------------- fused m1-build + m2 GEMM + BN stats
__device__ __forceinline__ void gate88(const float* __restrict__ Wa, const float* eaTl,
                                       int rg, int c0, float g[8][8]) {
  #pragma unroll
  for (int i = 0; i < 8; ++i)
    #pragma unroll
    for (int j = 0; j < 8; ++j) g[i][j] = 0.f;
  #pragma unroll
  for (int a = 0; a < 16; ++a) {
    float4 e0v = *(const float4*)&eaTl[a*132 + rg*8];
    float4 e1v = *(const float4*)&eaTl[a*132 + rg*8 + 4];
    float4 w0 = *(const float4*)(Wa + a*128 + c0);
    float4 w1 = *(const float4*)(Wa + a*128 + c0 + 64);
    float ev[8] = {e0v.x, e0v.y, e0v.z, e0v.w, e1v.x, e1v.y, e1v.z, e1v.w};
    float wv[8] = {w0.x, w0.y, w0.z, w0.w, w1.x, w1.y, w1.z, w1.w};
    #pragma unroll
    for (int i = 0; i < 8; ++i)
      #pragma unroll
      for (int j = 0; j < 8; ++j) g[i][j] = fmaf(ev[i], wv[j], g[i][j]);
  }
}

__launch_bounds__(256, 1)
__global__ void m12_fused(const float* __restrict__ Hr, const float* __restrict__ Hs,
                          const int* __restrict__ send, const int* __restrict__ recv,
                          const float* __restrict__ dist, const float* __restrict__ ea,
                          const float* __restrict__ w256, const float* __restrict__ W2,
                          const float* __restrict__ Wa1, const float* __restrict__ Wa2,
                          const float* __restrict__ b2, float* __restrict__ mout,
                          double* __restrict__ bn_sum, double* __restrict__ bn_sq)
{
  __shared__ float As[128*128];
  __shared__ float Ws[64*128];
  __shared__ float eaT[16*132];
  __shared__ float bS[512];
  __shared__ float bQ[512];
  __shared__ int   recvS[128];
  __shared__ int   sendS[128];
  __shared__ float distS[128];

  const int tid = threadIdx.x;
  const int e0b = blockIdx.x * 128;
  const int rg = tid >> 4;            // 0..15
  const int cg = tid & 15;            // 0..15
  const int c0 = cg * 4;
  const int sax = (rg & 3) << 3;

  if (tid < 128) {
    sendS[tid] = send[e0b + tid];
    recvS[tid] = recv[e0b + tid];
    distS[tid] = dist[e0b + tid];
  }
  {
    int et = tid >> 1, hf = (tid & 1) * 8;
    const float* ep = ea + (size_t)(e0b + et) * 16 + hf;
    float4 v0 = *(const float4*)(ep);
    float4 v1 = *(const float4*)(ep + 4);
    eaT[(hf+0)*132+et] = v0.x; eaT[(hf+1)*132+et] = v0.y;
    eaT[(hf+2)*132+et] = v0.z; eaT[(hf+3)*132+et] = v0.w;
    eaT[(hf+4)*132+et] = v1.x; eaT[(hf+5)*132+et] = v1.y;
    eaT[(hf+6)*132+et] = v1.z; eaT[(hf+7)*132+et] = v1.w;
  }
  __syncthreads();

  // ---- gate1 + m1 build into LDS ----
  {
    float g1[8][8];
    gate88(Wa1, eaT, rg, c0, g1);
    float4 wq0 = *(const float4*)(w256 + c0);
    float4 wq1 = *(const float4*)(w256 + c0 + 64);
    float wq[8] = {wq0.x, wq0.y, wq0.z, wq0.w, wq1.x, wq1.y, wq1.z, wq1.w};
    #pragma unroll
    for (int i = 0; i < 8; ++i) {
      int row = rg * 8 + i;
      int rid = recvS[row], sid = sendS[row];
      float dv = distS[row];
      const float* hr = Hr + (size_t)rid * 128;
      const float* hs = Hs + (size_t)sid * 128;
      float4 p0 = *(const float4*)(hr + c0);
      float4 p1 = *(const float4*)(hr + c0 + 64);
      float4 q0 = *(const float4*)(hs + c0);
      float4 q1 = *(const float4*)(hs + c0 + 64);
      float tv[8] = {p0.x+q0.x, p0.y+q0.y, p0.z+q0.z, p0.w+q0.w,
                     p1.x+q1.x, p1.y+q1.y, p1.z+q1.z, p1.w+q1.w};
      float rr[8];
      #pragma unroll
      for (int j = 0; j < 8; ++j) {
        float t = fmaf(dv, wq[j], tv[j]) * g1[i][j];
        rr[j] = t / (1.f + __expf(-t));          // silu
      }
      int ca = c0 ^ sax;
      *(float4*)&As[row*128 + ca]      = make_float4(rr[0], rr[1], rr[2], rr[3]);
      *(float4*)&As[row*128 + ca + 64] = make_float4(rr[4], rr[5], rr[6], rr[7]);
    }
  }

  // ---- m2 main GEMM: acc = A @ W2 ----
  float acc[8][8];
  #pragma unroll
  for (int i = 0; i < 8; ++i)
    #pragma unroll
    for (int j = 0; j < 8; ++j) acc[i][j] = 0.f;

  for (int h = 0; h < 2; ++h) {
    int k0 = h * 64;
    __syncthreads();
    {
      int cw = (tid & 31) * 4;
      int r0 = tid >> 5;
      #pragma unroll
      for (int it = 0; it < 8; ++it) {
        int r = it * 8 + r0;
        *(float4*)&Ws[r*128 + cw] = *(const float4*)(W2 + (size_t)(k0 + r) * 128 + cw);
      }
    }
    __syncthreads();
    #pragma unroll 2
    for (int s = 0; s < 16; ++s) {
      int kb = k0 + s * 4;
      float4 af[8];
      #pragma unroll
      for (int i = 0; i < 8; ++i)
        af[i] = *(const float4*)&As[(rg*8+i)*128 + ((kb & 127) ^ sax)];
      float4 wf0[4], wf1[4];
      #pragma unroll
      for (int kk = 0; kk < 4; ++kk) {
        wf0[kk] = *(const float4*)&Ws[(s*4+kk)*128 + c0];
        wf1[kk] = *(const float4*)&Ws[(s*4+kk)*128 + c0 + 64];
      }
      #pragma unroll
      for (int kk = 0; kk < 4; ++kk) {
        float4 w0 = wf0[kk], w1 = wf1[kk];
        #pragma unroll
        for (int i = 0; i < 8; ++i) {
          float av = ((const float*)&af[i])[kk];
          acc[i][0] = fmaf(av, w0.x, acc[i][0]);
          acc[i][1] = fmaf(av, w0.y, acc[i][1]);
          acc[i][2] = fmaf(av, w0.z, acc[i][2]);
          acc[i][3] = fmaf(av, w0.w, acc[i][3]);
          acc[i][4] = fmaf(av, w1.x, acc[i][4]);
          acc[i][5] = fmaf(av, w1.y, acc[i][5]);
          acc[i][6] = fmaf(av, w1.z, acc[i][6]);
          acc[i][7] = fmaf(av, w1.w, acc[i][7]);
        }
      }
    }
  }

  // ---- epilogue: gate2, bias, silu, BN stats, store ----
  float g2[8][8];
  gate88(Wa2, eaT, rg, c0, g2);
  float4 b20 = *(const float4*)(b2 + c0);
  float4 b21 = *(const float4*)(b2 + c0 + 64);
  float bvv[8] = {b20.x, b20.y, b20.z, b20.w, b21.x, b21.y, b21.z, b21.w};
  float sloc[8], qloc[8];
  #pragma unroll
  for (int j = 0; j < 8; ++j) { sloc[j] = 0.f; qloc[j] = 0.f; }

  #pragma unroll
  for (int i = 0; i < 8; ++i) {
    int row = rg * 8 + i;
    float rr[8];
    #pragma unroll
    for (int j = 0; j < 8; ++j) {
      float t = (acc[i][j] + bvv[j]) * g2[i][j];
      t = t / (1.f + __expf(-t));
      rr[j] = t;
      sloc[j] += t;
      qloc[j] = fmaf(t, t, qloc[j]);
    }
    float* op = mout + (size_t)(e0b + row) * 128;
    *(float4*)(op + c0)      = make_float4(rr[0], rr[1], rr[2], rr[3]);
    *(float4*)(op + c0 + 64) = make_float4(rr[4], rr[5], rr[6], rr[7]);
  }

  const int lane = tid & 63, wv_ = tid >> 6;
  #pragma unroll
  for (int j = 0; j < 8; ++j) {
    float s = sloc[j], q = qloc[j];
    s += __shfl_xor(s, 16); q += __shfl_xor(q, 16);
    s += __shfl_xor(s, 32); q += __shfl_xor(q, 32);
    if (lane < 16) {
      int col = (lane * 4) + (j & 3) + (j >> 2) * 64;
      bS[wv_ * 128 + col] = s;
      bQ[wv_ * 128 + col] = q;
    }
  }
  __syncthreads();
  if (tid < 128) {
    float s = bS[tid] + bS[128 + tid] + bS[256 + tid] + bS[384 + tid];
    float q = bQ[tid] + bQ[128 + tid] + bQ[256 + tid] + bQ[384 + tid];
    atomicAdd(&bn_sum[tid], (double)s);
    atomicAdd(&bn_sq[tid], (double)q);
  }
}

// ---------------------------------------------------------------- BN finalize
__global__ void bn_fin(const double* __restrict__ s, const double* __restrict__ q,
                       const float* __restrict__ g, const float* __restrict__ b,
                       float* __restrict__ sc, float* __restrict__ sh) {
  int c = threadIdx.x;
  double mu = s[c] * (1.0 / NE);
  double var = q[c] * (1.0 / NE) - mu * mu;
  if (var < 0.0) var = 0.0;
  float scale = (float)((double)g[c] / sqrt(var + 1e-5));
  sc[c] = scale;
  sh[c] = b[c] - (float)mu * scale;
}

// ---------------------------------------------------------------- fused BN-apply + attention + CSR-gather agg + softmax + ucat
__global__ void att_csr(const float* __restrict__ m, const float* __restrict__ sc,
                        const float* __restrict__ sh, const float* __restrict__ ea,
                        const float* __restrict__ iWx, const float* __restrict__ iWa,
                        const float* __restrict__ ibp,
                        const int* __restrict__ off, const int* __restrict__ csr,
                        const float* __restrict__ h, float* __restrict__ ucat) {
  int wave = threadIdx.x >> 6, lane = threadIdx.x & 63;
  int n = blockIdx.x * 4 + wave;
  if (n >= NN) return;
  float2 scv = *(const float2*)(sc + lane * 2);
  float2 shv = *(const float2*)(sh + lane * 2);
  float2 wv  = *(const float2*)(iWx + lane * 2);
  float wa = (lane < 16) ? iWa[lane] : 0.f;
  float ib = ibp[0];
  int o0 = off[n], o1 = off[n + 1];
  float acc0 = 0.f, acc1 = 0.f;
  for (int i = o0; i < o1; ++i) {
    int e = csr[i];
    float2 mv = *(const float2*)(m + (size_t)e * 128 + lane * 2);
    float a0 = fmaf(mv.x, scv.x, shv.x);
    float a1 = fmaf(mv.y, scv.y, shv.y);
    float s1 = a0 * wv.x + a1 * wv.y;
    float s2 = (lane < 16) ? ea[(size_t)e * 16 + lane] * wa : 0.f;
    #pragma unroll
    for (int o = 32; o > 0; o >>= 1) { s1 += __shfl_xor(s1, o); s2 += __shfl_xor(s2, o); }
    float att = 1.f / (1.f + __expf(-(s1 + ib) * s2));
    acc0 = fmaf(a0, att, acc0);
    acc1 = fmaf(a1, att, acc1);
  }
  float mx = fmaxf(acc0, acc1);
  #pragma unroll
  for (int o = 32; o > 0; o >>= 1) mx = fmaxf(mx, __shfl_xor(mx, o));
  float ex0 = __expf(acc0 - mx), ex1 = __expf(acc1 - mx);
  float s = ex0 + ex1;
  #pragma unroll
  for (int o = 32; o > 0; o >>= 1) s += __shfl_xor(s, o);
  float inv = 1.f / s;
  float2 hv = *(const float2*)(h + (size_t)n * 128 + lane * 2);
  *(float2*)(ucat + (size_t)n * 256 + lane * 2)       = make_float2(ex0 * inv * hv.x, ex1 * inv * hv.y);
  *(float2*)(ucat + (size_t)n * 256 + 128 + lane * 2) = make_float2(acc0, acc1);
}

// ---------------------------------------------------------------- graph pooling (parallel) + head
// 100 blocks x 256 thr; block covers nodes [blockIdx*100, +100); thread (r,j)
// accumulates column j over its strided nodes, flushing one atomic per graph boundary.
__global__ void pool2_k(const float* __restrict__ h, const int* __restrict__ batch,
                        float* __restrict__ gp) {
  int r = threadIdx.x >> 7;          // 0..1
  int j = threadIdx.x & 127;
  int n0 = blockIdx.x * 100;
  float acc = 0.f;
  int curg = -1;
  for (int k = 0; k < 50; ++k) {
    int n = n0 + 2 * k + r;
    int g = batch[n];
    if (g != curg) {
      if (curg >= 0) atomicAdd(&gp[curg * 128 + j], acc);
      acc = 0.f;
      curg = g;
    }
    acc += h[(size_t)n * 128 + j];
  }
  if (curg >= 0) atomicAdd(&gp[curg * 128 + j], acc);
}

__global__ void pp1_k(const float* __restrict__ gp, const float* __restrict__ W,
                      const float* __restrict__ b, float* __restrict__ gact) {
  __shared__ float gs[128];
  int g = blockIdx.x, j = threadIdx.x;   // 16 blocks x 128 threads
  gs[j] = gp[g * 128 + j];
  __syncthreads();
  float s = b[j];
  #pragma unroll 4
  for (int k = 0; k < 128; ++k) s = fmaf(gs[k], W[k * 128 + j], s);
  gact[g * 128 + j] = s / (1.f + __expf(-s));
}

__global__ void pp2_k(const float* __restrict__ gact, const float* __restrict__ w,
                      const float* __restrict__ b, float* __restrict__ out) {
  int t = threadIdx.x;
  if (t < NG) {
    float s = b[0];
    for (int j = 0; j < 128; ++j) s = fmaf(gact[t * 128 + j], w[j], s);
    out[t] = s;
  }
}

// ---------------------------------------------------------------- host
extern "C" void kernel_launch(void* const* d_in, const int* in_sizes, int n_in,
                              void* d_out, int out_size, void* d_ws, size_t ws_size,
                              hipStream_t stream)
{
  auto F = [&](int i) { return (const float*)d_in[i]; };
  auto I = [&](int i) { return (const int*)d_in[i]; };
  const float* x = F(0);
  const float* pos = F(1);
  const int* batch = I(2);
  const int* iei = I(3);
  const float* iea = F(4);
  const int* eei = I(5);
  const float* eea = F(6);
  const float* embinWx = F(7);  const float* embinWa = F(8);  const float* embinB = F(9);
  const float* emboutWx = F(10); const float* emboutWa = F(11); const float* emboutB = F(12);
  const float* m1Wx = F(13); const float* m1Wa = F(14); const float* m1B = F(15);
  const float* m2Wx = F(16); const float* m2Wa = F(17); const float* m2B = F(18);
  const float* bnG = F(19); const float* bnB = F(20);
  const float* infWx = F(21); const float* infWa = F(22); const float* infB = F(23);
  const float* uWx = F(24); const float* uWa = F(25); const float* uB = F(26);
  const float* ppWx = F(27); const float* ppWa = F(28); const float* ppB = F(29);
  const float* pp1W = F(30); const float* pp1B = F(31);
  const float* pp2W = F(32); const float* pp2B = F(33);
  float* out = (float*)d_out;

  float* ws = (float*)d_ws;
  size_t off = 0;
  auto alloc = [&](size_t n) { float* p = ws + off; off += (n + 63) & ~(size_t)63; return p; };
  float* eaI   = alloc((size_t)NE * 16);
  float* naI   = alloc((size_t)NN * 16);
  float* eaE   = alloc((size_t)NE * 16);
  float* naE   = alloc((size_t)NN * 16);
  float* hA    = alloc((size_t)NN * DD);
  float* hB    = alloc((size_t)NN * DD);
  float* nodeT = alloc((size_t)NN * 256);   // Hr|Hs during m12, then reused as ucat
  float* mbuf  = alloc((size_t)NE * DD);
  float* bnSC  = alloc(DD);
  float* bnSH  = alloc(DD);
  float* gp    = alloc(NG * DD);
  float* gact  = alloc(NG * DD);
  double* bnSum = (double*)alloc(512);      // 128+128 doubles
  double* bnSq  = bnSum + 128;
  int* degI = (int*)alloc(NN);
  int* degE = (int*)alloc(NN);
  int* offI = (int*)alloc(NN + 64);
  int* offE = (int*)alloc(NN + 64);
  int* curI = (int*)alloc(NN);
  int* curE = (int*)alloc(NN);
  int* csrI = (int*)alloc(NE);
  int* csrE = (int*)alloc(NE);

  float* Hr = nodeT;
  float* Hs = nodeT + (size_t)NN * DD;
  float* ucat = nodeT;

  hipMemsetAsync(naI, 0, (size_t)NN * 16 * 4, stream);
  hipMemsetAsync(naE, 0, (size_t)NN * 16 * 4, stream);
  hipMemsetAsync(degI, 0, NN * 4, stream);
  hipMemsetAsync(degE, 0, NN * 4, stream);
  hipMemsetAsync(gp, 0, NG * DD * 4, stream);

  const int* recvI = iei + NE;
  const int* recvE = eei + NE;

  count_k<<<(NE + 255) / 256, 256, 0, stream>>>(recvI, degI, NE);
  count_k<<<(NE + 255) / 256, 256, 0, stream>>>(recvE, degE, NE);
  scan_k<<<1, 256, 0, stream>>>(degI, offI, curI);
  scan_k<<<1, 256, 0, stream>>>(degE, offE, curE);
  fill_k<<<(NE + 255) / 256, 256, 0, stream>>>(recvI, curI, csrI, NE);
  fill_k<<<(NE + 255) / 256, 256, 0, stream>>>(recvE, curE, csrE, NE);

  sh_kernel<<<NE / 256, 256, 0, stream>>>(pos, iei, recvI, eaI, naI, NE);
  sh_kernel<<<NE / 256, 256, 0, stream>>>(pos, eei, recvE, eaE, naE, NE);
  na_fin<<<NN * 16 / 256, 256, 0, stream>>>(naI, degI);
  na_fin<<<NN * 16 / 256, 256, 0, stream>>>(naE, degE);

  const int gN = (NN + 63) / 64;

  k_emb<<<gN, 256, 0, stream>>>(x, naI, embinWx, embinWa, embinB, hA, NN);

  float* hin = hA;
  float* hout = hB;
  for (int l = 0; l < 6; ++l) {
    const bool internal = (l < 3);
    const int* send = internal ? iei : eei;
    const int* recv = internal ? recvI : recvE;
    const float* dist = internal ? iea : eea;
    const float* ea = internal ? eaI : eaE;
    const float* na = internal ? naI : naE;
    const int* coff = internal ? offI : offE;
    const int* ccsr = internal ? csrI : csrE;

    if (l == 3) {
      k_embout<<<gN, 256, 0, stream>>>(hin, naE, emboutWx, emboutWa, emboutB, hout, NN);
      float* t = hin; hin = hout; hout = t;
    }

    hipMemsetAsync(bnSum, 0, 2048, stream);

    const float* Wx1 = m1Wx + (size_t)l * 257 * 128;
    k_dual<<<gN, 256, 0, stream>>>(hin, Wx1, Wx1 + 128 * 128, m1B + l * 128, Hr, Hs, NN);
    m12_fused<<<NE / 128, 256, 0, stream>>>(
        Hr, Hs, send, recv, dist, ea,
        Wx1 + 256 * 128,
        m2Wx + (size_t)l * 128 * 128,
        m1Wa + (size_t)l * 16 * 128,
        m2Wa + (size_t)l * 16 * 128,
        m2B + l * 128,
        mbuf, bnSum, bnSq);
    bn_fin<<<1, 128, 0, stream>>>(bnSum, bnSq, bnG + l * 128, bnB + l * 128, bnSC, bnSH);
    att_csr<<<(NN + 3) / 4, 256, 0, stream>>>(mbuf, bnSC, bnSH, ea,
                                              infWx + l * 128, infWa + l * 16, infB + l,
                                              coff, ccsr, hin, ucat);
    k_upd<<<gN, 256, 0, stream>>>(ucat, na,
                                  uWx + (size_t)l * 256 * 128,
                                  uWa + (size_t)l * 16 * 128,
                                  uB + l * 128, hout, NN);
    float* t = hin; hin = hout; hout = t;
  }

  k_pp<<<gN, 256, 0, stream>>>(hin, naE, ppWx, ppWa, ppB, hout, NN);
  pool2_k<<<100, 256, 0, stream>>>(hout, batch, gp);
  pp1_k<<<NG, 128, 0, stream>>>(gp, pp1W, pp1B, gact);
  pp2_k<<<1, 64, 0, stream>>>(gact, pp2W, pp2B, out);
}

// Round 8
// 2031.346 us; speedup vs baseline: 4.9496x; 1.0089x over previous
//
#include <hip/hip_runtime.h>
#include <cstddef>

#define NN 10000
#define NE 160000
#define DD 128
#define NG 16

// ---------------------------------------------------------------- sh (edge spherical harmonics) + node-attr accumulation
__global__ void sh_kernel(const float* __restrict__ pos, const int* __restrict__ send,
                          const int* __restrict__ recv, float* __restrict__ ea,
                          float* __restrict__ naS, int E) {
  int e = blockIdx.x * 256 + threadIdx.x;
  if (e >= E) return;
  int s = send[e], r = recv[e];
  float rx = pos[s*3+0] - pos[r*3+0];
  float ry = pos[s*3+1] - pos[r*3+1];
  float rz = pos[s*3+2] - pos[r*3+2];
  float nrm = sqrtf(rx*rx + ry*ry + rz*rz) + 1e-8f;
  float x = rx / nrm, y = ry / nrm, z = rz / nrm;
  float x2 = x*x, y2 = y*y, z2 = z*z;
  float sh[16];
  sh[0] = 1.f;
  sh[1] = 1.7320508f * x;
  sh[2] = 1.7320508f * y;
  sh[3] = 1.7320508f * z;
  sh[4] = 3.8729833f * x * y;
  sh[5] = 3.8729833f * y * z;
  sh[6] = 1.118034f * (3.f * z2 - 1.f);
  sh[7] = 3.8729833f * x * z;
  sh[8] = 1.9364917f * (x2 - y2);
  sh[9] = 2.0916501f * y * (3.f * x2 - y2);
  sh[10] = 10.2469508f * x * y * z;
  sh[11] = 1.6201852f * y * (5.f * z2 - 1.f);
  sh[12] = 1.3228757f * (5.f * z2 - 3.f) * z;
  sh[13] = 1.6201852f * x * (5.f * z2 - 1.f);
  sh[14] = 5.1234754f * z * (x2 - y2);
  sh[15] = 2.0916501f * x * (x2 - 3.f * y2);
  float* ep = ea + (size_t)e * 16;
  *(float4*)(ep+0)  = make_float4(sh[0], sh[1], sh[2], sh[3]);
  *(float4*)(ep+4)  = make_float4(sh[4], sh[5], sh[6], sh[7]);
  *(float4*)(ep+8)  = make_float4(sh[8], sh[9], sh[10], sh[11]);
  *(float4*)(ep+12) = make_float4(sh[12], sh[13], sh[14], sh[15]);
  float* np = naS + (size_t)r * 16;
  #pragma unroll
  for (int k = 0; k < 16; ++k) atomicAdd(np + k, sh[k]);
}

__global__ void na_fin(float* __restrict__ na, const int* __restrict__ deg) {
  int idx = blockIdx.x * 256 + threadIdx.x;   // NN*16 total
  int n = idx >> 4, k = idx & 15;
  float c = fmaxf((float)deg[n], 1.f);
  float v = na[idx] / c;
  na[idx] = (k == 0) ? 1.f : v;
}

// ---------------------------------------------------------------- CSR build (reused across layers)
__global__ void count_k(const int* __restrict__ recv, int* __restrict__ deg, int E) {
  int e = blockIdx.x * 256 + threadIdx.x;
  if (e < E) atomicAdd(&deg[recv[e]], 1);
}

__global__ void scan_k(const int* __restrict__ deg, int* __restrict__ off, int* __restrict__ cur) {
  __shared__ int part[256];
  int tid = threadIdx.x;
  int base = tid * 40;
  int s = 0;
  for (int j = 0; j < 40; ++j) { int i = base + j; if (i < NN) s += deg[i]; }
  part[tid] = s;
  __syncthreads();
  if (tid == 0) {
    int run = 0;
    for (int i = 0; i < 256; ++i) { int v = part[i]; part[i] = run; run += v; }
  }
  __syncthreads();
  int run = part[tid];
  for (int j = 0; j < 40; ++j) {
    int i = base + j;
    if (i < NN) { off[i] = run; cur[i] = run; run += deg[i]; }
  }
  if (tid == 255) off[NN] = run;
}

__global__ void fill_k(const int* __restrict__ recv, int* __restrict__ cur,
                       int* __restrict__ csr, int E) {
  int e = blockIdx.x * 256 + threadIdx.x;
  if (e < E) { int p = atomicAdd(&cur[recv[e]], 1); csr[p] = e; }
}

// ---------------------------------------------------------------- node-level tensor-product GEMM body
// ACT: 0 = A@Wx (+bias); 1 = (A@Wx+b)*(gate@Wa); 2 = silu of that
template<int KX, int ACT>
__device__ __forceinline__ void tpg_body(const float* __restrict__ A, const float* __restrict__ gate,
                                         const float* __restrict__ Wx, const float* __restrict__ Wa,
                                         const float* __restrict__ bias, float* __restrict__ out, int M)
{
  constexpr int BK = 32;
  __shared__ float Asub[BK][64];
  __shared__ float Wsub[BK][128];
  __shared__ float Gt[ACT ? 64 : 1][ACT ? 16 : 1];
  __shared__ float WaS[ACT ? 16 : 1][ACT ? 128 : 1];

  const int tid = threadIdx.x;
  const int m0 = blockIdx.x * 64;
  const int col0 = (tid & 15) * 8;
  const int e0 = (tid >> 4) * 4;

  if constexpr (ACT > 0) {
    int e = tid >> 2, q = (tid & 3) * 4;
    int row = m0 + e; if (row >= M) row = M - 1;
    *(float4*)&Gt[e][q] = *(const float4*)(gate + (size_t)row * 16 + q);
    int wr = tid >> 4, wc = (tid & 15) * 8;
    *(float4*)&WaS[wr][wc]     = *(const float4*)(Wa + wr * 128 + wc);
    *(float4*)&WaS[wr][wc + 4] = *(const float4*)(Wa + wr * 128 + wc + 4);
  }

  float acc[4][8];
  #pragma unroll
  for (int i = 0; i < 4; ++i)
    #pragma unroll
    for (int j = 0; j < 8; ++j) acc[i][j] = 0.f;

  for (int k0 = 0; k0 < KX; k0 += BK) {
    __syncthreads();
    {
      int el = tid >> 2, koff = (tid & 3) * 8;
      int row = m0 + el; if (row >= M) row = M - 1;
      #pragma unroll
      for (int h4 = 0; h4 < 2; ++h4) {
        int k = k0 + koff + h4 * 4;
        if (k < KX) {
          float4 v = *(const float4*)(A + (size_t)row * KX + k);
          int kl = k - k0;
          Asub[kl+0][el] = v.x; Asub[kl+1][el] = v.y;
          Asub[kl+2][el] = v.z; Asub[kl+3][el] = v.w;
        }
      }
      int wr = tid >> 3, wc = (tid & 7) * 16;
      int k = k0 + wr;
      if (k < KX) {
        const float* wsrc = Wx + (size_t)k * 128 + wc;
        *(float4*)&Wsub[wr][wc]      = *(const float4*)(wsrc);
        *(float4*)&Wsub[wr][wc + 4]  = *(const float4*)(wsrc + 4);
        *(float4*)&Wsub[wr][wc + 8]  = *(const float4*)(wsrc + 8);
        *(float4*)&Wsub[wr][wc + 12] = *(const float4*)(wsrc + 12);
      }
    }
    __syncthreads();
    const int kc = (KX - k0 >= BK) ? BK : (KX - k0);
    if (kc == BK) {
      #pragma unroll
      for (int kk = 0; kk < BK; ++kk) {
        float4 a4 = *(const float4*)&Asub[kk][e0];
        float4 w0 = *(const float4*)&Wsub[kk][col0];
        float4 w1 = *(const float4*)&Wsub[kk][col0 + 4];
        float av[4] = {a4.x, a4.y, a4.z, a4.w};
        float wv[8] = {w0.x, w0.y, w0.z, w0.w, w1.x, w1.y, w1.z, w1.w};
        #pragma unroll
        for (int i = 0; i < 4; ++i)
          #pragma unroll
          for (int j = 0; j < 8; ++j) acc[i][j] = fmaf(av[i], wv[j], acc[i][j]);
      }
    } else {
      for (int kk = 0; kk < kc; ++kk) {
        float4 a4 = *(const float4*)&Asub[kk][e0];
        float4 w0 = *(const float4*)&Wsub[kk][col0];
        float4 w1 = *(const float4*)&Wsub[kk][col0 + 4];
        float av[4] = {a4.x, a4.y, a4.z, a4.w};
        float wv[8] = {w0.x, w0.y, w0.z, w0.w, w1.x, w1.y, w1.z, w1.w};
        #pragma unroll
        for (int i = 0; i < 4; ++i)
          #pragma unroll
          for (int j = 0; j < 8; ++j) acc[i][j] = fmaf(av[i], wv[j], acc[i][j]);
      }
    }
  }

  float gac[4][8];
  if constexpr (ACT > 0) {
    #pragma unroll
    for (int i = 0; i < 4; ++i)
      #pragma unroll
      for (int j = 0; j < 8; ++j) gac[i][j] = 0.f;
    #pragma unroll
    for (int k = 0; k < 16; ++k) {
      float4 w0 = *(const float4*)&WaS[k][col0];
      float4 w1 = *(const float4*)&WaS[k][col0 + 4];
      float wv[8] = {w0.x, w0.y, w0.z, w0.w, w1.x, w1.y, w1.z, w1.w};
      #pragma unroll
      for (int i = 0; i < 4; ++i) {
        float a = Gt[e0 + i][k];
        #pragma unroll
        for (int j = 0; j < 8; ++j) gac[i][j] = fmaf(a, wv[j], gac[i][j]);
      }
    }
  }

  float bv[8];
  if (bias) {
    float4 b0 = *(const float4*)(bias + col0);
    float4 b1 = *(const float4*)(bias + col0 + 4);
    bv[0]=b0.x; bv[1]=b0.y; bv[2]=b0.z; bv[3]=b0.w;
    bv[4]=b1.x; bv[5]=b1.y; bv[6]=b1.z; bv[7]=b1.w;
  } else {
    #pragma unroll
    for (int j = 0; j < 8; ++j) bv[j] = 0.f;
  }

  #pragma unroll
  for (int i = 0; i < 4; ++i) {
    int row = m0 + e0 + i;
    float res[8];
    #pragma unroll
    for (int j = 0; j < 8; ++j) {
      float t = acc[i][j] + bv[j];
      if constexpr (ACT > 0) t = t * gac[i][j];
      if constexpr (ACT == 2) t = t / (1.f + __expf(-t));
      res[j] = t;
    }
    if (row < M) {
      float* op = out + (size_t)row * 128 + col0;
      *(float4*)op       = make_float4(res[0], res[1], res[2], res[3]);
      *(float4*)(op + 4) = make_float4(res[4], res[5], res[6], res[7]);
    }
  }
}

// Distinctly-named wrappers (profiling attribution)
__global__ __launch_bounds__(256, 2) void k_emb(const float* A, const float* gate,
    const float* Wx, const float* Wa, const float* bias, float* out, int M)
{ tpg_body<16, 2>(A, gate, Wx, Wa, bias, out, M); }

__global__ __launch_bounds__(256, 2) void k_embout(const float* A, const float* gate,
    const float* Wx, const float* Wa, const float* bias, float* out, int M)
{ tpg_body<128, 1>(A, gate, Wx, Wa, bias, out, M); }

__global__ __launch_bounds__(256, 2) void k_upd(const float* A, const float* gate,
    const float* Wx, const float* Wa, const float* bias, float* out, int M)
{ tpg_body<256, 2>(A, gate, Wx, Wa, bias, out, M); }

__global__ __launch_bounds__(256, 2) void k_pp(const float* A, const float* gate,
    const float* Wx, const float* Wa, const float* bias, float* out, int M)
{ tpg_body<128, 2>(A, gate, Wx, Wa, bias, out, M); }

// ---------------------------------------------------------------- dual-output node GEMM: out1 = A@W1 + b1, out2 = A@W2 (KX=128)
__global__ __launch_bounds__(256, 2)
void k_dual(const float* __restrict__ A, const float* __restrict__ W1,
            const float* __restrict__ W2, const float* __restrict__ b1,
            float* __restrict__ out1, float* __restrict__ out2, int M)
{
  constexpr int BK = 32;
  constexpr int KX = 128;
  __shared__ float Asub[BK][64];
  __shared__ float Wsub[BK][128];
  __shared__ float W2sub[BK][128];

  const int tid = threadIdx.x;
  const int m0 = blockIdx.x * 64;
  const int col0 = (tid & 15) * 8;
  const int e0 = (tid >> 4) * 4;

  float acc[4][8], acc2[4][8];
  #pragma unroll
  for (int i = 0; i < 4; ++i)
    #pragma unroll
    for (int j = 0; j < 8; ++j) { acc[i][j] = 0.f; acc2[i][j] = 0.f; }

  for (int k0 = 0; k0 < KX; k0 += BK) {
    __syncthreads();
    {
      int el = tid >> 2, koff = (tid & 3) * 8;
      int row = m0 + el; if (row >= M) row = M - 1;
      #pragma unroll
      for (int h4 = 0; h4 < 2; ++h4) {
        int k = k0 + koff + h4 * 4;
        float4 v = *(const float4*)(A + (size_t)row * KX + k);
        int kl = k - k0;
        Asub[kl+0][el] = v.x; Asub[kl+1][el] = v.y;
        Asub[kl+2][el] = v.z; Asub[kl+3][el] = v.w;
      }
      int wr = tid >> 3, wc = (tid & 7) * 16;
      int k = k0 + wr;
      const float* w1src = W1 + (size_t)k * 128 + wc;
      *(float4*)&Wsub[wr][wc]      = *(const float4*)(w1src);
      *(float4*)&Wsub[wr][wc + 4]  = *(const float4*)(w1src + 4);
      *(float4*)&Wsub[wr][wc + 8]  = *(const float4*)(w1src + 8);
      *(float4*)&Wsub[wr][wc + 12] = *(const float4*)(w1src + 12);
      const float* w2src = W2 + (size_t)k * 128 + wc;
      *(float4*)&W2sub[wr][wc]      = *(const float4*)(w2src);
      *(float4*)&W2sub[wr][wc + 4]  = *(const float4*)(w2src + 4);
      *(float4*)&W2sub[wr][wc + 8]  = *(const float4*)(w2src + 8);
      *(float4*)&W2sub[wr][wc + 12] = *(const float4*)(w2src + 12);
    }
    __syncthreads();
    #pragma unroll
    for (int kk = 0; kk < BK; ++kk) {
      float4 a4 = *(const float4*)&Asub[kk][e0];
      float4 w0 = *(const float4*)&Wsub[kk][col0];
      float4 w1 = *(const float4*)&Wsub[kk][col0 + 4];
      float4 u0 = *(const float4*)&W2sub[kk][col0];
      float4 u1 = *(const float4*)&W2sub[kk][col0 + 4];
      float av[4] = {a4.x, a4.y, a4.z, a4.w};
      float wv[8] = {w0.x, w0.y, w0.z, w0.w, w1.x, w1.y, w1.z, w1.w};
      float uv[8] = {u0.x, u0.y, u0.z, u0.w, u1.x, u1.y, u1.z, u1.w};
      #pragma unroll
      for (int i = 0; i < 4; ++i) {
        #pragma unroll
        for (int j = 0; j < 8; ++j) {
          acc[i][j]  = fmaf(av[i], wv[j], acc[i][j]);
          acc2[i][j] = fmaf(av[i], uv[j], acc2[i][j]);
        }
      }
    }
  }

  float4 b0 = *(const float4*)(b1 + col0);
  float4 b1v = *(const float4*)(b1 + col0 + 4);
  float bv[8] = {b0.x, b0.y, b0.z, b0.w, b1v.x, b1v.y, b1v.z, b1v.w};

  #pragma unroll
  for (int i = 0; i < 4; ++i) {
    int row = m0 + e0 + i;
    if (row < M) {
      float* o1 = out1 + (size_t)row * 128 + col0;
      float* o2 = out2 + (size_t)row * 128 + col0;
      *(float4*)o1       = make_float4(acc[i][0]+bv[0], acc[i][1]+bv[1], acc[i][2]+bv[2], acc[i][3]+bv[3]);
      *(float4*)(o1 + 4) = make_float4(acc[i][4]+bv[4], acc[i][5]+bv[5], acc[i][6]+bv[6], acc[i][7]+bv[7]);
      *(float4*)o2       = make_float4(acc2[i][0], acc2[i][1], acc2[i][2], acc2[i][3]);
      *(float4*)(o2 + 4) = make_float4(acc2[i][4], acc2[i][5], acc2[i][6], acc2[i][7]);
    }
  }
}

// ---------------------------------------------------------------- fused m1-build + m2 GEMM + BN stats
// v2: W2 read directly from global (L1/L2-cached, shared by all blocks) — no Ws LDS tile.
// LDS = As(64K) + eaT(8.25K) + bS/bQ(4K) + idx(1.5K) ≈ 77.8 KB -> 2 blocks/CU.
__device__ __forceinline__ void gate88(const float* __restrict__ Wa, const float* eaTl,
                                       int rg, int c0, float g[8][8]) {
  #pragma unroll
  for (int i = 0; i < 8; ++i)
    #pragma unroll
    for (int j = 0; j < 8; ++j) g[i][j] = 0.f;
  #pragma unroll
  for (int a = 0; a < 16; ++a) {
    float4 e0v = *(const float4*)&eaTl[a*132 + rg*8];
    float4 e1v = *(const float4*)&eaTl[a*132 + rg*8 + 4];
    float4 w0 = *(const float4*)(Wa + a*128 + c0);
    float4 w1 = *(const float4*)(Wa + a*128 + c0 + 64);
    float ev[8] = {e0v.x, e0v.y, e0v.z, e0v.w, e1v.x, e1v.y, e1v.z, e1v.w};
    float wv[8] = {w0.x, w0.y, w0.z, w0.w, w1.x, w1.y, w1.z, w1.w};
    #pragma unroll
    for (int i = 0; i < 8; ++i)
      #pragma unroll
      for (int j = 0; j < 8; ++j) g[i][j] = fmaf(ev[i], wv[j], g[i][j]);
  }
}

__launch_bounds__(256, 2)
__global__ void m12_fused(const float* __restrict__ Hr, const float* __restrict__ Hs,
                          const int* __restrict__ send, const int* __restrict__ recv,
                          const float* __restrict__ dist, const float* __restrict__ ea,
                          const float* __restrict__ w256, const float* __restrict__ W2,
                          const float* __restrict__ Wa1, const float* __restrict__ Wa2,
                          const float* __restrict__ b2, float* __restrict__ mout,
                          double* __restrict__ bn_sum, double* __restrict__ bn_sq)
{
  __shared__ float As[128*128];
  __shared__ float eaT[16*132];
  __shared__ float bS[512];
  __shared__ float bQ[512];
  __shared__ int   recvS[128];
  __shared__ int   sendS[128];
  __shared__ float distS[128];

  const int tid = threadIdx.x;
  const int e0b = blockIdx.x * 128;
  const int rg = tid >> 4;            // 0..15
  const int cg = tid & 15;            // 0..15
  const int c0 = cg * 4;
  const int sax = (rg & 3) << 3;

  if (tid < 128) {
    sendS[tid] = send[e0b + tid];
    recvS[tid] = recv[e0b + tid];
    distS[tid] = dist[e0b + tid];
  }
  {
    int et = tid >> 1, hf = (tid & 1) * 8;
    const float* ep = ea + (size_t)(e0b + et) * 16 + hf;
    float4 v0 = *(const float4*)(ep);
    float4 v1 = *(const float4*)(ep + 4);
    eaT[(hf+0)*132+et] = v0.x; eaT[(hf+1)*132+et] = v0.y;
    eaT[(hf+2)*132+et] = v0.z; eaT[(hf+3)*132+et] = v0.w;
    eaT[(hf+4)*132+et] = v1.x; eaT[(hf+5)*132+et] = v1.y;
    eaT[(hf+6)*132+et] = v1.z; eaT[(hf+7)*132+et] = v1.w;
  }
  __syncthreads();

  // ---- gate1 + m1 build into LDS ----
  {
    float g1[8][8];
    gate88(Wa1, eaT, rg, c0, g1);
    float4 wq0 = *(const float4*)(w256 + c0);
    float4 wq1 = *(const float4*)(w256 + c0 + 64);
    float wq[8] = {wq0.x, wq0.y, wq0.z, wq0.w, wq1.x, wq1.y, wq1.z, wq1.w};
    #pragma unroll
    for (int i = 0; i < 8; ++i) {
      int row = rg * 8 + i;
      int rid = recvS[row], sid = sendS[row];
      float dv = distS[row];
      const float* hr = Hr + (size_t)rid * 128;
      const float* hs = Hs + (size_t)sid * 128;
      float4 p0 = *(const float4*)(hr + c0);
      float4 p1 = *(const float4*)(hr + c0 + 64);
      float4 q0 = *(const float4*)(hs + c0);
      float4 q1 = *(const float4*)(hs + c0 + 64);
      float tv[8] = {p0.x+q0.x, p0.y+q0.y, p0.z+q0.z, p0.w+q0.w,
                     p1.x+q1.x, p1.y+q1.y, p1.z+q1.z, p1.w+q1.w};
      float rr[8];
      #pragma unroll
      for (int j = 0; j < 8; ++j) {
        float t = fmaf(dv, wq[j], tv[j]) * g1[i][j];
        rr[j] = t / (1.f + __expf(-t));          // silu
      }
      int ca = c0 ^ sax;
      *(float4*)&As[row*128 + ca]      = make_float4(rr[0], rr[1], rr[2], rr[3]);
      *(float4*)&As[row*128 + ca + 64] = make_float4(rr[4], rr[5], rr[6], rr[7]);
    }
  }

  __syncthreads();

  // ---- m2 main GEMM: acc = A @ W2, W2 streamed from global (L1/L2) ----
  float acc[8][8];
  #pragma unroll
  for (int i = 0; i < 8; ++i)
    #pragma unroll
    for (int j = 0; j < 8; ++j) acc[i][j] = 0.f;

  #pragma unroll 2
  for (int s = 0; s < 32; ++s) {
    int kb = s * 4;
    float4 af[8];
    #pragma unroll
    for (int i = 0; i < 8; ++i)
      af[i] = *(const float4*)&As[(rg*8+i)*128 + (kb ^ sax)];
    float4 wf0[4], wf1[4];
    #pragma unroll
    for (int kk = 0; kk < 4; ++kk) {
      const float* wrow = W2 + (size_t)(kb + kk) * 128;
      wf0[kk] = *(const float4*)(wrow + c0);
      wf1[kk] = *(const float4*)(wrow + c0 + 64);
    }
    #pragma unroll
    for (int kk = 0; kk < 4; ++kk) {
      float4 w0 = wf0[kk], w1 = wf1[kk];
      #pragma unroll
      for (int i = 0; i < 8; ++i) {
        float av = ((const float*)&af[i])[kk];
        acc[i][0] = fmaf(av, w0.x, acc[i][0]);
        acc[i][1] = fmaf(av, w0.y, acc[i][1]);
        acc[i][2] = fmaf(av, w0.z, acc[i][2]);
        acc[i][3] = fmaf(av, w0.w, acc[i][3]);
        acc[i][4] = fmaf(av, w1.x, acc[i][4]);
        acc[i][5] = fmaf(av, w1.y, acc[i][5]);
        acc[i][6] = fmaf(av, w1.z, acc[i][6]);
        acc[i][7] = fmaf(av, w1.w, acc[i][7]);
      }
    }
  }

  // ---- epilogue: gate2, bias, silu, BN stats, store ----
  float g2[8][8];
  gate88(Wa2, eaT, rg, c0, g2);
  float4 b20 = *(const float4*)(b2 + c0);
  float4 b21 = *(const float4*)(b2 + c0 + 64);
  float bvv[8] = {b20.x, b20.y, b20.z, b20.w, b21.x, b21.y, b21.z, b21.w};
  float sloc[8], qloc[8];
  #pragma unroll
  for (int j = 0; j < 8; ++j) { sloc[j] = 0.f; qloc[j] = 0.f; }

  #pragma unroll
  for (int i = 0; i < 8; ++i) {
    int row = rg * 8 + i;
    float rr[8];
    #pragma unroll
    for (int j = 0; j < 8; ++j) {
      float t = (acc[i][j] + bvv[j]) * g2[i][j];
      t = t / (1.f + __expf(-t));
      rr[j] = t;
      sloc[j] += t;
      qloc[j] = fmaf(t, t, qloc[j]);
    }
    float* op = mout + (size_t)(e0b + row) * 128;
    *(float4*)(op + c0)      = make_float4(rr[0], rr[1], rr[2], rr[3]);
    *(float4*)(op + c0 + 64) = make_float4(rr[4], rr[5], rr[6], rr[7]);
  }

  const int lane = tid & 63, wv_ = tid >> 6;
  #pragma unroll
  for (int j = 0; j < 8; ++j) {
    float s = sloc[j], q = qloc[j];
    s += __shfl_xor(s, 16); q += __shfl_xor(q, 16);
    s += __shfl_xor(s, 32); q += __shfl_xor(q, 32);
    if (lane < 16) {
      int col = (lane * 4) + (j & 3) + (j >> 2) * 64;
      bS[wv_ * 128 + col] = s;
      bQ[wv_ * 128 + col] = q;
    }
  }
  __syncthreads();
  if (tid < 128) {
    float s = bS[tid] + bS[128 + tid] + bS[256 + tid] + bS[384 + tid];
    float q = bQ[tid] + bQ[128 + tid] + bQ[256 + tid] + bQ[384 + tid];
    atomicAdd(&bn_sum[tid], (double)s);
    atomicAdd(&bn_sq[tid], (double)q);
  }
}

// ---------------------------------------------------------------- BN finalize
__global__ void bn_fin(const double* __restrict__ s, const double* __restrict__ q,
                       const float* __restrict__ g, const float* __restrict__ b,
                       float* __restrict__ sc, float* __restrict__ sh) {
  int c = threadIdx.x;
  double mu = s[c] * (1.0 / NE);
  double var = q[c] * (1.0 / NE) - mu * mu;
  if (var < 0.0) var = 0.0;
  float scale = (float)((double)g[c] / sqrt(var + 1e-5));
  sc[c] = scale;
  sh[c] = b[c] - (float)mu * scale;
}

// ---------------------------------------------------------------- fused BN-apply + attention + CSR-gather agg + softmax + ucat
__global__ void att_csr(const float* __restrict__ m, const float* __restrict__ sc,
                        const float* __restrict__ sh, const float* __restrict__ ea,
                        const float* __restrict__ iWx, const float* __restrict__ iWa,
                        const float* __restrict__ ibp,
                        const int* __restrict__ off, const int* __restrict__ csr,
                        const float* __restrict__ h, float* __restrict__ ucat) {
  int wave = threadIdx.x >> 6, lane = threadIdx.x & 63;
  int n = blockIdx.x * 4 + wave;
  if (n >= NN) return;
  float2 scv = *(const float2*)(sc + lane * 2);
  float2 shv = *(const float2*)(sh + lane * 2);
  float2 wv  = *(const float2*)(iWx + lane * 2);
  float wa = (lane < 16) ? iWa[lane] : 0.f;
  float ib = ibp[0];
  int o0 = off[n], o1 = off[n + 1];
  float acc0 = 0.f, acc1 = 0.f;
  for (int i = o0; i < o1; ++i) {
    int e = csr[i];
    float2 mv = *(const float2*)(m + (size_t)e * 128 + lane * 2);
    float a0 = fmaf(mv.x, scv.x, shv.x);
    float a1 = fmaf(mv.y, scv.y, shv.y);
    float s1 = a0 * wv.x + a1 * wv.y;
    float s2 = (lane < 16) ? ea[(size_t)e * 16 + lane] * wa : 0.f;
    #pragma unroll
    for (int o = 32; o > 0; o >>= 1) { s1 += __shfl_xor(s1, o); s2 += __shfl_xor(s2, o); }
    float att = 1.f / (1.f + __expf(-(s1 + ib) * s2));
    acc0 = fmaf(a0, att, acc0);
    acc1 = fmaf(a1, att, acc1);
  }
  float mx = fmaxf(acc0, acc1);
  #pragma unroll
  for (int o = 32; o > 0; o >>= 1) mx = fmaxf(mx, __shfl_xor(mx, o));
  float ex0 = __expf(acc0 - mx), ex1 = __expf(acc1 - mx);
  float s = ex0 + ex1;
  #pragma unroll
  for (int o = 32; o > 0; o >>= 1) s += __shfl_xor(s, o);
  float inv = 1.f / s;
  float2 hv = *(const float2*)(h + (size_t)n * 128 + lane * 2);
  *(float2*)(ucat + (size_t)n * 256 + lane * 2)       = make_float2(ex0 * inv * hv.x, ex1 * inv * hv.y);
  *(float2*)(ucat + (size_t)n * 256 + 128 + lane * 2) = make_float2(acc0, acc1);
}

// ---------------------------------------------------------------- graph pooling (parallel) + head
__global__ void pool2_k(const float* __restrict__ h, const int* __restrict__ batch,
                        float* __restrict__ gp) {
  int r = threadIdx.x >> 7;          // 0..1
  int j = threadIdx.x & 127;
  int n0 = blockIdx.x * 100;
  float acc = 0.f;
  int curg = -1;
  for (int k = 0; k < 50; ++k) {
    int n = n0 + 2 * k + r;
    int g = batch[n];
    if (g != curg) {
      if (curg >= 0) atomicAdd(&gp[curg * 128 + j], acc);
      acc = 0.f;
      curg = g;
    }
    acc += h[(size_t)n * 128 + j];
  }
  if (curg >= 0) atomicAdd(&gp[curg * 128 + j], acc);
}

__global__ void pp1_k(const float* __restrict__ gp, const float* __restrict__ W,
                      const float* __restrict__ b, float* __restrict__ gact) {
  __shared__ float gs[128];
  int g = blockIdx.x, j = threadIdx.x;   // 16 blocks x 128 threads
  gs[j] = gp[g * 128 + j];
  __syncthreads();
  float s = b[j];
  #pragma unroll 4
  for (int k = 0; k < 128; ++k) s = fmaf(gs[k], W[k * 128 + j], s);
  gact[g * 128 + j] = s / (1.f + __expf(-s));
}

__global__ void pp2_k(const float* __restrict__ gact, const float* __restrict__ w,
                      const float* __restrict__ b, float* __restrict__ out) {
  int t = threadIdx.x;
  if (t < NG) {
    float s = b[0];
    for (int j = 0; j < 128; ++j) s = fmaf(gact[t * 128 + j], w[j], s);
    out[t] = s;
  }
}

// ---------------------------------------------------------------- host
extern "C" void kernel_launch(void* const* d_in, const int* in_sizes, int n_in,
                              void* d_out, int out_size, void* d_ws, size_t ws_size,
                              hipStream_t stream)
{
  auto F = [&](int i) { return (const float*)d_in[i]; };
  auto I = [&](int i) { return (const int*)d_in[i]; };
  const float* x = F(0);
  const float* pos = F(1);
  const int* batch = I(2);
  const int* iei = I(3);
  const float* iea = F(4);
  const int* eei = I(5);
  const float* eea = F(6);
  const float* embinWx = F(7);  const float* embinWa = F(8);  const float* embinB = F(9);
  const float* emboutWx = F(10); const float* emboutWa = F(11); const float* emboutB = F(12);
  const float* m1Wx = F(13); const float* m1Wa = F(14); const float* m1B = F(15);
  const float* m2Wx = F(16); const float* m2Wa = F(17); const float* m2B = F(18);
  const float* bnG = F(19); const float* bnB = F(20);
  const float* infWx = F(21); const float* infWa = F(22); const float* infB = F(23);
  const float* uWx = F(24); const float* uWa = F(25); const float* uB = F(26);
  const float* ppWx = F(27); const float* ppWa = F(28); const float* ppB = F(29);
  const float* pp1W = F(30); const float* pp1B = F(31);
  const float* pp2W = F(32); const float* pp2B = F(33);
  float* out = (float*)d_out;

  float* ws = (float*)d_ws;
  size_t off = 0;
  auto alloc = [&](size_t n) { float* p = ws + off; off += (n + 63) & ~(size_t)63; return p; };
  float* eaI   = alloc((size_t)NE * 16);
  float* naI   = alloc((size_t)NN * 16);
  float* eaE   = alloc((size_t)NE * 16);
  float* naE   = alloc((size_t)NN * 16);
  float* hA    = alloc((size_t)NN * DD);
  float* hB    = alloc((size_t)NN * DD);
  float* nodeT = alloc((size_t)NN * 256);   // Hr|Hs during m12, then reused as ucat
  float* mbuf  = alloc((size_t)NE * DD);
  float* bnSC  = alloc(DD);
  float* bnSH  = alloc(DD);
  float* gp    = alloc(NG * DD);
  float* gact  = alloc(NG * DD);
  double* bnSum = (double*)alloc(512);      // 128+128 doubles
  double* bnSq  = bnSum + 128;
  int* degI = (int*)alloc(NN);
  int* degE = (int*)alloc(NN);
  int* offI = (int*)alloc(NN + 64);
  int* offE = (int*)alloc(NN + 64);
  int* curI = (int*)alloc(NN);
  int* curE = (int*)alloc(NN);
  int* csrI = (int*)alloc(NE);
  int* csrE = (int*)alloc(NE);

  float* Hr = nodeT;
  float* Hs = nodeT + (size_t)NN * DD;
  float* ucat = nodeT;

  hipMemsetAsync(naI, 0, (size_t)NN * 16 * 4, stream);
  hipMemsetAsync(naE, 0, (size_t)NN * 16 * 4, stream);
  hipMemsetAsync(degI, 0, NN * 4, stream);
  hipMemsetAsync(degE, 0, NN * 4, stream);
  hipMemsetAsync(gp, 0, NG * DD * 4, stream);

  const int* recvI = iei + NE;
  const int* recvE = eei + NE;

  count_k<<<(NE + 255) / 256, 256, 0, stream>>>(recvI, degI, NE);
  count_k<<<(NE + 255) / 256, 256, 0, stream>>>(recvE, degE, NE);
  scan_k<<<1, 256, 0, stream>>>(degI, offI, curI);
  scan_k<<<1, 256, 0, stream>>>(degE, offE, curE);
  fill_k<<<(NE + 255) / 256, 256, 0, stream>>>(recvI, curI, csrI, NE);
  fill_k<<<(NE + 255) / 256, 256, 0, stream>>>(recvE, curE, csrE, NE);

  sh_kernel<<<NE / 256, 256, 0, stream>>>(pos, iei, recvI, eaI, naI, NE);
  sh_kernel<<<NE / 256, 256, 0, stream>>>(pos, eei, recvE, eaE, naE, NE);
  na_fin<<<NN * 16 / 256, 256, 0, stream>>>(naI, degI);
  na_fin<<<NN * 16 / 256, 256, 0, stream>>>(naE, degE);

  const int gN = (NN + 63) / 64;

  k_emb<<<gN, 256, 0, stream>>>(x, naI, embinWx, embinWa, embinB, hA, NN);

  float* hin = hA;
  float* hout = hB;
  for (int l = 0; l < 6; ++l) {
    const bool internal = (l < 3);
    const int* send = internal ? iei : eei;
    const int* recv = internal ? recvI : recvE;
    const float* dist = internal ? iea : eea;
    const float* ea = internal ? eaI : eaE;
    const float* na = internal ? naI : naE;
    const int* coff = internal ? offI : offE;
    const int* ccsr = internal ? csrI : csrE;

    if (l == 3) {
      k_embout<<<gN, 256, 0, stream>>>(hin, naE, emboutWx, emboutWa, emboutB, hout, NN);
      float* t = hin; hin = hout; hout = t;
    }

    hipMemsetAsync(bnSum, 0, 2048, stream);

    const float* Wx1 = m1Wx + (size_t)l * 257 * 128;
    k_dual<<<gN, 256, 0, stream>>>(hin, Wx1, Wx1 + 128 * 128, m1B + l * 128, Hr, Hs, NN);
    m12_fused<<<NE / 128, 256, 0, stream>>>(
        Hr, Hs, send, recv, dist, ea,
        Wx1 + 256 * 128,
        m2Wx + (size_t)l * 128 * 128,
        m1Wa + (size_t)l * 16 * 128,
        m2Wa + (size_t)l * 16 * 128,
        m2B + l * 128,
        mbuf, bnSum, bnSq);
    bn_fin<<<1, 128, 0, stream>>>(bnSum, bnSq, bnG + l * 128, bnB + l * 128, bnSC, bnSH);
    att_csr<<<(NN + 3) / 4, 256, 0, stream>>>(mbuf, bnSC, bnSH, ea,
                                              infWx + l * 128, infWa + l * 16, infB + l,
                                              coff, ccsr, hin, ucat);
    k_upd<<<gN, 256, 0, stream>>>(ucat, na,
                                  uWx + (size_t)l * 256 * 128,
                                  uWa + (size_t)l * 16 * 128,
                                  uB + l * 128, hout, NN);
    float* t = hin; hin = hout; hout = t;
  }

  k_pp<<<gN, 256, 0, stream>>>(hin, naE, ppWx, ppWa, ppB, hout, NN);
  pool2_k<<<100, 256, 0, stream>>>(hout, batch, gp);
  pp1_k<<<NG, 128, 0, stream>>>(gp, pp1W, pp1B, gact);
  pp2_k<<<1, 64, 0, stream>>>(gact, pp2W, pp2B, out);
}